// Round 1
// baseline (536.383 us; speedup 1.0000x reference)
//
#include <hip/hip_runtime.h>
#include <hip/hip_bf16.h>
#include <stdint.h>

using short8 = __attribute__((ext_vector_type(8))) short;
using f32x4  = __attribute__((ext_vector_type(4))) float;

__device__ inline unsigned short f2bf(float f) {
  union { float f; unsigned int u; } v; v.f = f;
  unsigned int r = v.u + 0x7FFFu + ((v.u >> 16) & 1u);
  return (unsigned short)(r >> 16);
}
__device__ inline float bf2f(unsigned short u) {
  union { unsigned int u; float f; } v; v.u = ((unsigned int)u) << 16;
  return v.f;
}

// ---------------- elementwise f32 -> bf16 ----------------
__global__ __launch_bounds__(256) void k_convert(const float* __restrict__ in,
                                                 unsigned short* __restrict__ out, int n) {
  int i = (blockIdx.x * 256 + threadIdx.x) * 8;
  if (i >= n) return;
  float4 a = *(const float4*)(in + i);
  float4 b = *(const float4*)(in + i + 4);
  short8 o;
  o[0] = (short)f2bf(a.x); o[1] = (short)f2bf(a.y);
  o[2] = (short)f2bf(a.z); o[3] = (short)f2bf(a.w);
  o[4] = (short)f2bf(b.x); o[5] = (short)f2bf(b.y);
  o[6] = (short)f2bf(b.z); o[7] = (short)f2bf(b.w);
  *(short8*)(out + i) = o;
}

// ---------------- transpose-convert: in[R][C] f32 -> out[C][R] bf16 ----------------
__global__ __launch_bounds__(256) void k_transpose(const float* __restrict__ in,
                                                   unsigned short* __restrict__ out,
                                                   int R, int C) {
  __shared__ float t[32][33];
  int c0 = blockIdx.x * 32, r0 = blockIdx.y * 32;
  int cl = threadIdx.x & 31, rl = threadIdx.x >> 5;  // rl 0..7
  for (int p = 0; p < 4; ++p)
    t[rl + p * 8][cl] = in[(size_t)(r0 + rl + p * 8) * C + c0 + cl];
  __syncthreads();
  for (int p = 0; p < 4; ++p)
    out[(size_t)(c0 + rl + p * 8) * R + r0 + cl] = f2bf(t[cl][rl + p * 8]);
}

// ---------------- bf16 GEMM: C[M,N] = A[M,K] * Bt[N,K]^T ----------------
// MODE 0: scatter epilogue into q/k/v ws [B,H,T,D] bf16 (for N=3072 QKV GEMM)
// MODE 1: plain fp32 C write
template <int MODE>
__global__ __launch_bounds__(256) void k_gemm(
    const unsigned short* __restrict__ A, const unsigned short* __restrict__ Bt,
    float* __restrict__ Cf,
    unsigned short* __restrict__ q_ws, unsigned short* __restrict__ k_ws,
    unsigned short* __restrict__ v_ws, int M, int N, int K) {
  __shared__ __align__(16) unsigned short As[128][40];  // +8 pad: 2-way max conflicts
  __shared__ __align__(16) unsigned short Bs[128][40];
  const int tid = threadIdx.x;
  const int w = tid >> 6, l = tid & 63;
  const int lr = l & 15, lg = l >> 4;
  const int wr = w >> 1, wc = w & 1;
  const int m0 = blockIdx.y * 128, n0 = blockIdx.x * 128;
  f32x4 acc[4][4] = {};
  for (int k0 = 0; k0 < K; k0 += 32) {
#pragma unroll
    for (int rep = 0; rep < 2; ++rep) {
      int e = rep * 2048 + tid * 8;
      int row = e >> 5, kk = e & 31;
      *(short8*)&As[row][kk] = *(const short8*)(A + (size_t)(m0 + row) * K + k0 + kk);
      *(short8*)&Bs[row][kk] = *(const short8*)(Bt + (size_t)(n0 + row) * K + k0 + kk);
    }
    __syncthreads();
    short8 af[4], bf[4];
#pragma unroll
    for (int i = 0; i < 4; ++i) af[i] = *(const short8*)&As[wr * 64 + i * 16 + lr][lg * 8];
#pragma unroll
    for (int j = 0; j < 4; ++j) bf[j] = *(const short8*)&Bs[wc * 64 + j * 16 + lr][lg * 8];
#pragma unroll
    for (int i = 0; i < 4; ++i)
#pragma unroll
      for (int j = 0; j < 4; ++j)
        acc[i][j] = __builtin_amdgcn_mfma_f32_16x16x32_bf16(af[i], bf[j], acc[i][j], 0, 0, 0);
    __syncthreads();
  }
  // C/D layout (measured): col = lane&15, row = (lane>>4)*4 + reg
  if constexpr (MODE == 1) {
#pragma unroll
    for (int i = 0; i < 4; ++i)
#pragma unroll
      for (int j = 0; j < 4; ++j)
#pragma unroll
        for (int r = 0; r < 4; ++r) {
          int row = m0 + wr * 64 + i * 16 + lg * 4 + r;
          int col = n0 + wc * 64 + j * 16 + lr;
          Cf[(size_t)row * N + col] = acc[i][j][r];
        }
  } else {
#pragma unroll
    for (int i = 0; i < 4; ++i)
#pragma unroll
      for (int j = 0; j < 4; ++j)
#pragma unroll
        for (int r = 0; r < 4; ++r) {
          int row = m0 + wr * 64 + i * 16 + lg * 4 + r;
          int col = n0 + wc * 64 + j * 16 + lr;
          int b = row >> 11, t = row & 2047;
          int sect = col >> 10, c = col & 1023;
          int h = c >> 6, d = c & 63;
          size_t idx = (((size_t)(b * 16 + h)) * 2048 + t) * 64 + d;
          unsigned short val = f2bf(acc[i][j][r]);
          if (sect == 0) q_ws[idx] = val;
          else if (sect == 1) k_ws[idx] = val;
          else v_ws[idx] = val;
        }
  }
}

// ---------------- causal flash attention, bf16 MFMA ----------------
// grid: (T/128, B*H); block 256 = 4 waves, each wave owns 32 q-rows.
__global__ __launch_bounds__(256) void k_attn(
    const unsigned short* __restrict__ q_ws, const unsigned short* __restrict__ k_ws,
    const unsigned short* __restrict__ v_ws, unsigned short* __restrict__ y_ws) {
  __shared__ __align__(16) unsigned short Ks[64][72];      // [t][d], padded
  __shared__ __align__(16) unsigned short Vs[64][72];      // [d][t] (transposed), padded
  __shared__ __align__(16) unsigned short Ps[4][32][72];   // per-wave P, padded
  const int bh = blockIdx.y;
  const int q0 = blockIdx.x * 128;
  const int tid = threadIdx.x, w = tid >> 6, l = tid & 63;
  const int lr = l & 15, lg = l >> 4;
  const unsigned short* Qp = q_ws + ((size_t)bh * 2048 + q0 + w * 32) * 64;
  const unsigned short* Kp = k_ws + (size_t)bh * 2048 * 64;
  const unsigned short* Vp = v_ws + (size_t)bh * 2048 * 64;
  // Q fragments, pre-scaled by 1/sqrt(D)=0.125 (power of 2: exact in bf16)
  short8 qf[2][2];
#pragma unroll
  for (int i = 0; i < 2; ++i)
#pragma unroll
    for (int ks = 0; ks < 2; ++ks) {
      short8 v = *(const short8*)(Qp + (i * 16 + lr) * 64 + ks * 32 + lg * 8);
#pragma unroll
      for (int e = 0; e < 8; ++e)
        v[e] = (short)f2bf(bf2f((unsigned short)v[e]) * 0.125f);
      qf[i][ks] = v;
    }
  float m_st[2][4], l_st[2][4];
  f32x4 o[2][4] = {};
#pragma unroll
  for (int i = 0; i < 2; ++i)
#pragma unroll
    for (int r = 0; r < 4; ++r) { m_st[i][r] = -INFINITY; l_st[i][r] = 0.f; }
  const int ktmax = (q0 + 127) >> 6;
  for (int kt = 0; kt <= ktmax; ++kt) {
    // stage K tile [64][64] and V tile transposed -> Vs[d][t]
#pragma unroll
    for (int rep = 0; rep < 2; ++rep) {
      int e = rep * 2048 + tid * 8;
      int row = e >> 6, d0 = e & 63;
      *(short8*)&Ks[row][d0] = *(const short8*)(Kp + (size_t)(kt * 64 + row) * 64 + d0);
      short8 vv = *(const short8*)(Vp + (size_t)(kt * 64 + row) * 64 + d0);
#pragma unroll
      for (int e2 = 0; e2 < 8; ++e2) Vs[d0 + e2][row] = (unsigned short)vv[e2];
    }
    __syncthreads();
    // S = Q * K^T  (K row-major == B^T layout for MFMA)
    f32x4 s[2][4] = {};
#pragma unroll
    for (int ks = 0; ks < 2; ++ks) {
      short8 kf[4];
#pragma unroll
      for (int j = 0; j < 4; ++j) kf[j] = *(const short8*)&Ks[j * 16 + lr][ks * 32 + lg * 8];
#pragma unroll
      for (int i = 0; i < 2; ++i)
#pragma unroll
        for (int j = 0; j < 4; ++j)
          s[i][j] = __builtin_amdgcn_mfma_f32_16x16x32_bf16(qf[i][ks], kf[j], s[i][j], 0, 0, 0);
    }
    // causal mask + online softmax
#pragma unroll
    for (int i = 0; i < 2; ++i) {
      int rowbase = q0 + w * 32 + i * 16 + lg * 4;
#pragma unroll
      for (int j = 0; j < 4; ++j) {
        int gcol = kt * 64 + j * 16 + lr;
#pragma unroll
        for (int r = 0; r < 4; ++r)
          if (gcol > rowbase + r) s[i][j][r] = -INFINITY;
      }
#pragma unroll
      for (int r = 0; r < 4; ++r) {
        float v0 = fmaxf(fmaxf(s[i][0][r], s[i][1][r]), fmaxf(s[i][2][r], s[i][3][r]));
#pragma unroll
        for (int dd = 1; dd < 16; dd <<= 1) v0 = fmaxf(v0, __shfl_xor(v0, dd));
        float nm = fmaxf(m_st[i][r], v0);
        float corr = __expf(m_st[i][r] - nm);
        m_st[i][r] = nm;
        float rsum = 0.f;
#pragma unroll
        for (int j = 0; j < 4; ++j) {
          float p = __expf(s[i][j][r] - nm);
          s[i][j][r] = p;
          rsum += p;
        }
#pragma unroll
        for (int dd = 1; dd < 16; dd <<= 1) rsum += __shfl_xor(rsum, dd);
        l_st[i][r] = l_st[i][r] * corr + rsum;
#pragma unroll
        for (int jd = 0; jd < 4; ++jd) o[i][jd][r] *= corr;
      }
      // P -> LDS (bf16) to re-fragment for PV A-operand
#pragma unroll
      for (int j = 0; j < 4; ++j)
#pragma unroll
        for (int r = 0; r < 4; ++r)
          Ps[w][i * 16 + lg * 4 + r][j * 16 + lr] = f2bf(s[i][j][r]);
    }
    __syncthreads();
    // O += P * V   (Vs[d][t] == B^T layout)
#pragma unroll
    for (int ks = 0; ks < 2; ++ks) {
      short8 pf[2], vf[4];
#pragma unroll
      for (int i = 0; i < 2; ++i) pf[i] = *(const short8*)&Ps[w][i * 16 + lr][ks * 32 + lg * 8];
#pragma unroll
      for (int jd = 0; jd < 4; ++jd) vf[jd] = *(const short8*)&Vs[jd * 16 + lr][ks * 32 + lg * 8];
#pragma unroll
      for (int i = 0; i < 2; ++i)
#pragma unroll
        for (int jd = 0; jd < 4; ++jd)
          o[i][jd] = __builtin_amdgcn_mfma_f32_16x16x32_bf16(pf[i], vf[jd], o[i][jd], 0, 0, 0);
    }
    __syncthreads();
  }
  // epilogue: y[b, t, h*64+d] bf16
  int b = bh >> 4, h = bh & 15;
#pragma unroll
  for (int i = 0; i < 2; ++i)
#pragma unroll
    for (int r = 0; r < 4; ++r) {
      int grow = q0 + w * 32 + i * 16 + lg * 4 + r;
      float inv = 1.f / l_st[i][r];
#pragma unroll
      for (int jd = 0; jd < 4; ++jd)
        y_ws[((size_t)(b * 2048 + grow)) * 1024 + h * 64 + jd * 16 + lr] =
            f2bf(o[i][jd][r] * inv);
    }
}

extern "C" void kernel_launch(void* const* d_in, const int* in_sizes, int n_in,
                              void* d_out, int out_size, void* d_ws, size_t ws_size,
                              hipStream_t stream) {
  const float* x      = (const float*)d_in[0];
  const float* w_qkv  = (const float*)d_in[1];
  const float* w_proj = (const float*)d_in[2];
  float* out = (float*)d_out;
  const int Mm = 8192, Cc = 1024;  // B*T, C
  unsigned short* ws     = (unsigned short*)d_ws;
  unsigned short* xb     = ws;                                  // [8192,1024] bf16
  unsigned short* wqkvT  = xb + (size_t)Mm * Cc;                // [3072,1024] bf16
  unsigned short* wprojT = wqkvT + (size_t)3 * Cc * Cc;         // [1024,1024] bf16
  unsigned short* q_ws   = wprojT + (size_t)Cc * Cc;            // [B,H,T,D] bf16
  unsigned short* k_ws   = q_ws + (size_t)Mm * Cc;
  unsigned short* v_ws   = k_ws + (size_t)Mm * Cc;
  unsigned short* y_ws   = xb;  // alias: xb dead after GEMM1

  k_convert<<<dim3(Mm * Cc / 8 / 256), 256, 0, stream>>>(x, xb, Mm * Cc);
  k_transpose<<<dim3(3 * Cc / 32, Cc / 32), 256, 0, stream>>>(w_qkv, wqkvT, Cc, 3 * Cc);
  k_transpose<<<dim3(Cc / 32, Cc / 32), 256, 0, stream>>>(w_proj, wprojT, Cc, Cc);
  k_gemm<0><<<dim3(3 * Cc / 128, Mm / 128), 256, 0, stream>>>(
      xb, wqkvT, nullptr, q_ws, k_ws, v_ws, Mm, 3 * Cc, Cc);
  k_attn<<<dim3(2048 / 128, 4 * 16), 256, 0, stream>>>(q_ws, k_ws, v_ws, y_ws);
  k_gemm<1><<<dim3(Cc / 128, Mm / 128), 256, 0, stream>>>(
      y_ws, wprojT, out, nullptr, nullptr, nullptr, Mm, Cc, Cc);
}

// Round 3
// 399.893 us; speedup vs baseline: 1.3413x; 1.3413x over previous
//
#include <hip/hip_runtime.h>
#include <hip/hip_bf16.h>
#include <stdint.h>

using short8 = __attribute__((ext_vector_type(8))) short;
using s4vec  = __attribute__((ext_vector_type(4))) short;
using f32x4  = __attribute__((ext_vector_type(4))) float;

__device__ inline unsigned short f2bf(float f) {
  union { float f; unsigned int u; } v; v.f = f;
  unsigned int r = v.u + 0x7FFFu + ((v.u >> 16) & 1u);
  return (unsigned short)(r >> 16);
}
__device__ inline float bf2f(unsigned short u) {
  union { unsigned int u; float f; } v; v.u = ((unsigned int)u) << 16;
  return v.f;
}
__device__ inline unsigned int pack_bf16(float lo, float hi) {
  union { __hip_bfloat162 b; unsigned int u; } cv;
  cv.b = __float22bfloat162_rn(make_float2(lo, hi));  // .x -> low 16 bits
  return cv.u;
}

// ---------------- elementwise f32 -> bf16 ----------------
__global__ __launch_bounds__(256) void k_convert(const float* __restrict__ in,
                                                 unsigned short* __restrict__ out, int n) {
  int i = (blockIdx.x * 256 + threadIdx.x) * 8;
  if (i >= n) return;
  float4 a = *(const float4*)(in + i);
  float4 b = *(const float4*)(in + i + 4);
  short8 o;
  o[0] = (short)f2bf(a.x); o[1] = (short)f2bf(a.y);
  o[2] = (short)f2bf(a.z); o[3] = (short)f2bf(a.w);
  o[4] = (short)f2bf(b.x); o[5] = (short)f2bf(b.y);
  o[6] = (short)f2bf(b.z); o[7] = (short)f2bf(b.w);
  *(short8*)(out + i) = o;
}

// ---------------- transpose-convert: in[R][C] f32 -> out[C][R] bf16 ----------------
__global__ __launch_bounds__(256) void k_transpose(const float* __restrict__ in,
                                                   unsigned short* __restrict__ out,
                                                   int R, int C) {
  __shared__ float t[32][33];
  int c0 = blockIdx.x * 32, r0 = blockIdx.y * 32;
  int cl = threadIdx.x & 31, rl = threadIdx.x >> 5;  // rl 0..7
  for (int p = 0; p < 4; ++p)
    t[rl + p * 8][cl] = in[(size_t)(r0 + rl + p * 8) * C + c0 + cl];
  __syncthreads();
  for (int p = 0; p < 4; ++p)
    out[(size_t)(c0 + rl + p * 8) * R + r0 + cl] = f2bf(t[cl][rl + p * 8]);
}

// ---------------- bf16 GEMM: C[M,N] = A[M,K] * Bt[N,K]^T ----------------
// MODE 0: scatter epilogue into q/k ws [B,H,T,D] and v ws [B,H,D,T] (V transposed)
// MODE 1: plain fp32 C write
template <int MODE>
__global__ __launch_bounds__(256) void k_gemm(
    const unsigned short* __restrict__ A, const unsigned short* __restrict__ Bt,
    float* __restrict__ Cf,
    unsigned short* __restrict__ q_ws, unsigned short* __restrict__ k_ws,
    unsigned short* __restrict__ v_ws, int M, int N, int K) {
  __shared__ __align__(16) unsigned short As[128][40];
  __shared__ __align__(16) unsigned short Bs[128][40];
  const int tid = threadIdx.x;
  const int w = tid >> 6, l = tid & 63;
  const int lr = l & 15, lg = l >> 4;
  const int wr = w >> 1, wc = w & 1;
  const int m0 = blockIdx.y * 128, n0 = blockIdx.x * 128;
  f32x4 acc[4][4] = {};
  for (int k0 = 0; k0 < K; k0 += 32) {
#pragma unroll
    for (int rep = 0; rep < 2; ++rep) {
      int e = rep * 2048 + tid * 8;
      int row = e >> 5, kk = e & 31;
      *(short8*)&As[row][kk] = *(const short8*)(A + (size_t)(m0 + row) * K + k0 + kk);
      *(short8*)&Bs[row][kk] = *(const short8*)(Bt + (size_t)(n0 + row) * K + k0 + kk);
    }
    __syncthreads();
    short8 af[4], bf[4];
#pragma unroll
    for (int i = 0; i < 4; ++i) af[i] = *(const short8*)&As[wr * 64 + i * 16 + lr][lg * 8];
#pragma unroll
    for (int j = 0; j < 4; ++j) bf[j] = *(const short8*)&Bs[wc * 64 + j * 16 + lr][lg * 8];
#pragma unroll
    for (int i = 0; i < 4; ++i)
#pragma unroll
      for (int j = 0; j < 4; ++j)
        acc[i][j] = __builtin_amdgcn_mfma_f32_16x16x32_bf16(af[i], bf[j], acc[i][j], 0, 0, 0);
    __syncthreads();
  }
  // C/D layout: col = lane&15, row = (lane>>4)*4 + reg
  if constexpr (MODE == 1) {
#pragma unroll
    for (int i = 0; i < 4; ++i)
#pragma unroll
      for (int j = 0; j < 4; ++j)
#pragma unroll
        for (int r = 0; r < 4; ++r) {
          int row = m0 + wr * 64 + i * 16 + lg * 4 + r;
          int col = n0 + wc * 64 + j * 16 + lr;
          Cf[(size_t)row * N + col] = acc[i][j][r];
        }
  } else {
#pragma unroll
    for (int i = 0; i < 4; ++i)
#pragma unroll
      for (int j = 0; j < 4; ++j) {
        int row0 = m0 + wr * 64 + i * 16 + lg * 4;
        int col = n0 + wc * 64 + j * 16 + lr;
        int b = row0 >> 11, t = row0 & 2047;
        int sect = col >> 10, c = col & 1023;
        int h = c >> 6, d = c & 63;
        if (sect == 2) {
          s4vec pv;
#pragma unroll
          for (int r = 0; r < 4; ++r) pv[r] = (short)f2bf(acc[i][j][r]);
          *(s4vec*)(v_ws + (((size_t)(b * 16 + h)) * 64 + d) * 2048 + t) = pv;
        } else {
          unsigned short* dst = (sect == 0) ? q_ws : k_ws;
#pragma unroll
          for (int r = 0; r < 4; ++r)
            dst[(((size_t)(b * 16 + h)) * 2048 + t + r) * 64 + d] = f2bf(acc[i][j][r]);
        }
      }
  }
}

// ---------------- causal flash attention, swapped-QK^T, in-register softmax ----------------
// grid: (T/128, B*H); block 256 = 4 waves, wave owns 32 q-rows. KVBLK=64.
__global__ __launch_bounds__(256) void k_attn(
    const unsigned short* __restrict__ q_ws, const unsigned short* __restrict__ k_ws,
    const unsigned short* __restrict__ vt_ws, unsigned short* __restrict__ y_ws) {
  __shared__ __align__(16) unsigned short Ks[64][72];  // K tile [t][d]
  __shared__ __align__(16) unsigned short Vs[64][72];  // V^T tile [d][t]
  const int bh = blockIdx.y;
  const int q0 = blockIdx.x * 128;
  const int tid = threadIdx.x, w = tid >> 6, l = tid & 63;
  const int lr = l & 15, lg = l >> 4;
  const unsigned short* Qp = q_ws + ((size_t)bh * 2048 + q0 + w * 32) * 64;
  const unsigned short* Kp = k_ws + (size_t)bh * 2048 * 64;
  const unsigned short* Vtp = vt_ws + (size_t)bh * 64 * 2048;
  // Q fragments (B-operand), pre-scaled by 1/sqrt(64)=0.125 (exact in bf16)
  short8 qf[2][2];
#pragma unroll
  for (int i = 0; i < 2; ++i)
#pragma unroll
    for (int ks = 0; ks < 2; ++ks) {
      short8 v = *(const short8*)(Qp + (i * 16 + lr) * 64 + ks * 32 + lg * 8);
#pragma unroll
      for (int e = 0; e < 8; ++e)
        v[e] = (short)f2bf(bf2f((unsigned short)v[e]) * 0.125f);
      qf[i][ks] = v;
    }
  float m_st[2] = {-INFINITY, -INFINITY}, l_st[2] = {0.f, 0.f};
  f32x4 o[2][4] = {};
  const int ktmax = (q0 + 127) >> 6;
  const int qhi = q0 + w * 32 + 31;
  for (int kt = 0; kt <= ktmax; ++kt) {
    __syncthreads();  // previous compute done before overwrite
#pragma unroll
    for (int rep = 0; rep < 2; ++rep) {
      int e = rep * 2048 + tid * 8;
      int row = e >> 6, cc = e & 63;
      *(short8*)&Ks[row][cc] = *(const short8*)(Kp + (size_t)(kt * 64 + row) * 64 + cc);
      *(short8*)&Vs[row][cc] = *(const short8*)(Vtp + (size_t)row * 2048 + kt * 64 + cc);
    }
    __syncthreads();
    if (kt * 64 > qhi) continue;  // wave-level causal skip (barriers already passed)
    // S^T = K * Q^T : s[j][i] holds S[k = kt*64 + j*16 + lg*4 + r][q = q0+w*32 + i*16 + lr]
    f32x4 s[4][2] = {};
#pragma unroll
    for (int ks = 0; ks < 2; ++ks) {
      short8 kf[4];
#pragma unroll
      for (int j = 0; j < 4; ++j) kf[j] = *(const short8*)&Ks[j * 16 + lr][ks * 32 + lg * 8];
#pragma unroll
      for (int j = 0; j < 4; ++j)
#pragma unroll
        for (int i = 0; i < 2; ++i)
          s[j][i] = __builtin_amdgcn_mfma_f32_16x16x32_bf16(kf[j], qf[i][ks], s[j][i], 0, 0, 0);
    }
    if (kt * 64 + 63 > q0 + w * 32) {  // tile touches the diagonal -> mask
#pragma unroll
      for (int j = 0; j < 4; ++j)
#pragma unroll
        for (int i = 0; i < 2; ++i) {
          int gq = q0 + w * 32 + i * 16 + lr;
          int gk0 = kt * 64 + j * 16 + lg * 4;
#pragma unroll
          for (int r = 0; r < 4; ++r)
            if (gk0 + r > gq) s[j][i][r] = -INFINITY;
        }
    }
    union PaU { unsigned int u[4]; short8 v; };
    PaU pa[2][2];
#pragma unroll
    for (int i = 0; i < 2; ++i) {
      // row q = i*16+lr stats: in-lane fold over 16 + 2 shfl (replicas differ in lg)
      float tm = s[0][i][0];
#pragma unroll
      for (int j = 0; j < 4; ++j)
#pragma unroll
        for (int r = 0; r < 4; ++r) tm = fmaxf(tm, s[j][i][r]);
      tm = fmaxf(tm, __shfl_xor(tm, 16));
      tm = fmaxf(tm, __shfl_xor(tm, 32));
      float nm = fmaxf(m_st[i], tm);
      float corr = __expf(m_st[i] - nm);
      m_st[i] = nm;
      float ts = 0.f;
#pragma unroll
      for (int j = 0; j < 4; ++j)
#pragma unroll
        for (int r = 0; r < 4; ++r) {
          float p = __expf(s[j][i][r] - nm);
          s[j][i][r] = p;
          ts += p;
        }
      ts += __shfl_xor(ts, 16);
      ts += __shfl_xor(ts, 32);
      l_st[i] = l_st[i] * corr + ts;
      // redistribute corr to o-row holders (o rows: q = i*16 + lg*4 + r)
      float co[4];
#pragma unroll
      for (int r = 0; r < 4; ++r) co[r] = __shfl(corr, (l & 48) | (lg * 4 + r));
#pragma unroll
      for (int jd = 0; jd < 4; ++jd)
#pragma unroll
        for (int r = 0; r < 4; ++r) o[i][jd][r] *= co[r];
      // pack P to bf16 pairs: pk[j][h] = {P[k=j*16+lg*4+2h], P[k=..+2h+1]} for q=i*16+lr
      unsigned int pk[4][2];
#pragma unroll
      for (int j = 0; j < 4; ++j)
#pragma unroll
        for (int h = 0; h < 2; ++h)
          pk[j][h] = pack_bf16(s[j][i][2 * h], s[j][i][2 * h + 1]);
      // gather A-operand words: lane needs P[q=i*16+lr][k = ks*32 + lg*8 + 2*wi +{0,1}]
#pragma unroll
      for (int ks = 0; ks < 2; ++ks)
#pragma unroll
        for (int wi = 0; wi < 4; ++wi) {
          int src = ((lg & 1) * 2 + (wi >> 1)) * 16 + lr;
          unsigned int w0 = __shfl(pk[ks * 2][wi & 1], src);
          unsigned int w1 = __shfl(pk[ks * 2 + 1][wi & 1], src);
          pa[i][ks].u[wi] = (lg >> 1) ? w1 : w0;
        }
    }
    // O += P * V  (A = P frags, B = V^T from Vs[d][t])
#pragma unroll
    for (int ks = 0; ks < 2; ++ks) {
      short8 vf[4];
#pragma unroll
      for (int jd = 0; jd < 4; ++jd) vf[jd] = *(const short8*)&Vs[jd * 16 + lr][ks * 32 + lg * 8];
#pragma unroll
      for (int i = 0; i < 2; ++i)
#pragma unroll
        for (int jd = 0; jd < 4; ++jd)
          o[i][jd] = __builtin_amdgcn_mfma_f32_16x16x32_bf16(pa[i][ks].v, vf[jd], o[i][jd], 0, 0, 0);
    }
  }
  // epilogue: o rows q = i*16+lg*4+r, cols d = jd*16+lr
  int b = bh >> 4, h = bh & 15;
#pragma unroll
  for (int i = 0; i < 2; ++i) {
    float li[4];
#pragma unroll
    for (int r = 0; r < 4; ++r)
      li[r] = 1.f / __shfl(l_st[i], (l & 48) | (lg * 4 + r));
#pragma unroll
    for (int r = 0; r < 4; ++r) {
      int grow = q0 + w * 32 + i * 16 + lg * 4 + r;
#pragma unroll
      for (int jd = 0; jd < 4; ++jd)
        y_ws[((size_t)(b * 2048 + grow)) * 1024 + h * 64 + jd * 16 + lr] =
            f2bf(o[i][jd][r] * li[r]);
    }
  }
}

extern "C" void kernel_launch(void* const* d_in, const int* in_sizes, int n_in,
                              void* d_out, int out_size, void* d_ws, size_t ws_size,
                              hipStream_t stream) {
  const float* x      = (const float*)d_in[0];
  const float* w_qkv  = (const float*)d_in[1];
  const float* w_proj = (const float*)d_in[2];
  float* out = (float*)d_out;
  const int Mm = 8192, Cc = 1024;  // B*T, C
  unsigned short* ws     = (unsigned short*)d_ws;
  unsigned short* xb     = ws;                                  // [8192,1024] bf16
  unsigned short* wqkvT  = xb + (size_t)Mm * Cc;                // [3072,1024] bf16
  unsigned short* wprojT = wqkvT + (size_t)3 * Cc * Cc;         // [1024,1024] bf16
  unsigned short* q_ws   = wprojT + (size_t)Cc * Cc;            // [B,H,T,D] bf16
  unsigned short* k_ws   = q_ws + (size_t)Mm * Cc;              // [B,H,T,D] bf16
  unsigned short* vt_ws  = k_ws + (size_t)Mm * Cc;              // [B,H,D,T] bf16 (transposed)
  unsigned short* y_ws   = xb;  // alias: xb dead after GEMM1

  k_convert<<<dim3(Mm * Cc / 8 / 256), 256, 0, stream>>>(x, xb, Mm * Cc);
  k_transpose<<<dim3(3 * Cc / 32, Cc / 32), 256, 0, stream>>>(w_qkv, wqkvT, Cc, 3 * Cc);
  k_transpose<<<dim3(Cc / 32, Cc / 32), 256, 0, stream>>>(w_proj, wprojT, Cc, Cc);
  k_gemm<0><<<dim3(3 * Cc / 128, Mm / 128), 256, 0, stream>>>(
      xb, wqkvT, nullptr, q_ws, k_ws, vt_ws, Mm, 3 * Cc, Cc);
  k_attn<<<dim3(2048 / 128, 4 * 16), 256, 0, stream>>>(q_ws, k_ws, vt_ws, y_ws);
  k_gemm<1><<<dim3(Cc / 128, Mm / 128), 256, 0, stream>>>(
      y_ws, wprojT, out, nullptr, nullptr, nullptr, Mm, Cc, Cc);
}

// Round 8
// 311.532 us; speedup vs baseline: 1.7218x; 1.2836x over previous
//
#include <hip/hip_runtime.h>
#include <hip/hip_bf16.h>
#include <stdint.h>

using short8 = __attribute__((ext_vector_type(8))) short;
using s4vec  = __attribute__((ext_vector_type(4))) short;
using f32x4  = __attribute__((ext_vector_type(4))) float;

__device__ inline unsigned short f2bf(float f) {
  union { float f; unsigned int u; } v; v.f = f;
  unsigned int r = v.u + 0x7FFFu + ((v.u >> 16) & 1u);
  return (unsigned short)(r >> 16);
}
__device__ inline float bf2f(unsigned short u) {
  union { unsigned int u; float f; } v; v.u = ((unsigned int)u) << 16;
  return v.f;
}
__device__ inline unsigned int pack_bf16(float lo, float hi) {
  union { __hip_bfloat162 b; unsigned int u; } cv;
  cv.b = __float22bfloat162_rn(make_float2(lo, hi));  // .x -> low 16 bits
  return cv.u;
}

#if __has_builtin(__builtin_amdgcn_global_load_lds)
#define HAVE_GLOAD_LDS 1
// CK-style: global (AS1) per-lane src, wave-uniform LDS (AS3) base; HW writes base+lane*16.
__device__ inline void gload_lds16(const unsigned short* g, unsigned short* l) {
  auto gp = (const __attribute__((address_space(1))) unsigned int*)(uintptr_t)g;
  auto lp = (__attribute__((address_space(3))) unsigned int*)(uintptr_t)l;
  __builtin_amdgcn_global_load_lds(gp, lp, 16, 0, 0);
}
#else
#define HAVE_GLOAD_LDS 0
#endif

// ---------------- elementwise f32 -> bf16 ----------------
__global__ __launch_bounds__(256) void k_convert(const float* __restrict__ in,
                                                 unsigned short* __restrict__ out, int n) {
  int i = (blockIdx.x * 256 + threadIdx.x) * 8;
  if (i >= n) return;
  float4 a = *(const float4*)(in + i);
  float4 b = *(const float4*)(in + i + 4);
  short8 o;
  o[0] = (short)f2bf(a.x); o[1] = (short)f2bf(a.y);
  o[2] = (short)f2bf(a.z); o[3] = (short)f2bf(a.w);
  o[4] = (short)f2bf(b.x); o[5] = (short)f2bf(b.y);
  o[6] = (short)f2bf(b.z); o[7] = (short)f2bf(b.w);
  *(short8*)(out + i) = o;
}

// ---------------- transpose-convert: in[R][C] f32 -> out[C][R] bf16 ----------------
__global__ __launch_bounds__(256) void k_transpose(const float* __restrict__ in,
                                                   unsigned short* __restrict__ out,
                                                   int R, int C) {
  __shared__ float t[32][33];
  int c0 = blockIdx.x * 32, r0 = blockIdx.y * 32;
  int cl = threadIdx.x & 31, rl = threadIdx.x >> 5;  // rl 0..7
  for (int p = 0; p < 4; ++p)
    t[rl + p * 8][cl] = in[(size_t)(r0 + rl + p * 8) * C + c0 + cl];
  __syncthreads();
  for (int p = 0; p < 4; ++p)
    out[(size_t)(c0 + rl + p * 8) * R + r0 + cl] = f2bf(t[cl][rl + p * 8]);
}

// ---------------- bf16 GEMM (m97 structure): C[M,N] = A[M,K] * Bt[N,K]^T ----------------
// Unpadded [128][32] LDS tiles staged via global_load_lds width-16.
// MODE 0: scatter epilogue into q/k ws [B,H,T,D] and v ws [B,H,D,T] (V transposed)
// MODE 1: plain fp32 C write
template <int MODE>
__global__ __launch_bounds__(256) void k_gemm(
    const unsigned short* __restrict__ A, const unsigned short* __restrict__ Bt,
    float* __restrict__ Cf,
    unsigned short* __restrict__ q_ws, unsigned short* __restrict__ k_ws,
    unsigned short* __restrict__ v_ws, int M, int N, int K) {
  __shared__ __align__(16) unsigned short As[128][32];
  __shared__ __align__(16) unsigned short Bs[128][32];
  const int tid = threadIdx.x;
  const int w = tid >> 6, l = tid & 63;
  const int lr = l & 15, lg = l >> 4;
  const int wr = w >> 1, wc = w & 1;
  const int m0 = blockIdx.y * 128, n0 = blockIdx.x * 128;
  f32x4 acc[4][4] = {};
  for (int k0 = 0; k0 < K; k0 += 32) {
#pragma unroll
    for (int rep = 0; rep < 2; ++rep) {
      int e = rep * 2048 + tid * 8;  // flat short index; row = e>>5, kk = e&31
      int row = e >> 5, kk = e & 31;
      const unsigned short* ga = A + (size_t)(m0 + row) * K + k0 + kk;
      const unsigned short* gb = Bt + (size_t)(n0 + row) * K + k0 + kk;
#if HAVE_GLOAD_LDS
      // wave-uniform LDS base (shorts): rep*2048 + w*512; lane writes base + lane*16B
      unsigned short* la = &As[0][0] + rep * 2048 + w * 512;
      unsigned short* lb = &Bs[0][0] + rep * 2048 + w * 512;
      gload_lds16(ga, la);
      gload_lds16(gb, lb);
#else
      *(short8*)&As[row][kk] = *(const short8*)ga;
      *(short8*)&Bs[row][kk] = *(const short8*)gb;
#endif
    }
    __syncthreads();
    short8 af[4], bf[4];
#pragma unroll
    for (int i = 0; i < 4; ++i) af[i] = *(const short8*)&As[wr * 64 + i * 16 + lr][lg * 8];
#pragma unroll
    for (int j = 0; j < 4; ++j) bf[j] = *(const short8*)&Bs[wc * 64 + j * 16 + lr][lg * 8];
#pragma unroll
    for (int i = 0; i < 4; ++i)
#pragma unroll
      for (int j = 0; j < 4; ++j)
        acc[i][j] = __builtin_amdgcn_mfma_f32_16x16x32_bf16(af[i], bf[j], acc[i][j], 0, 0, 0);
    __syncthreads();
  }
  // C/D layout: col = lane&15, row = (lane>>4)*4 + reg
  if constexpr (MODE == 1) {
#pragma unroll
    for (int i = 0; i < 4; ++i)
#pragma unroll
      for (int j = 0; j < 4; ++j)
#pragma unroll
        for (int r = 0; r < 4; ++r) {
          int row = m0 + wr * 64 + i * 16 + lg * 4 + r;
          int col = n0 + wc * 64 + j * 16 + lr;
          Cf[(size_t)row * N + col] = acc[i][j][r];
        }
  } else {
#pragma unroll
    for (int i = 0; i < 4; ++i)
#pragma unroll
      for (int j = 0; j < 4; ++j) {
        int row0 = m0 + wr * 64 + i * 16 + lg * 4;
        int col = n0 + wc * 64 + j * 16 + lr;
        int b = row0 >> 11, t = row0 & 2047;
        int sect = col >> 10, c = col & 1023;
        int h = c >> 6, d = c & 63;
        if (sect == 2) {
          s4vec pv;
#pragma unroll
          for (int r = 0; r < 4; ++r) pv[r] = (short)f2bf(acc[i][j][r]);
          *(s4vec*)(v_ws + (((size_t)(b * 16 + h)) * 64 + d) * 2048 + t) = pv;
        } else {
          unsigned short* dst = (sect == 0) ? q_ws : k_ws;
#pragma unroll
          for (int r = 0; r < 4; ++r)
            dst[(((size_t)(b * 16 + h)) * 2048 + t + r) * 64 + d] = f2bf(acc[i][j][r]);
        }
      }
  }
}

// ---------------- causal flash attention, swapped-QK^T, in-register softmax ----------------
// grid: (bh=64, qt=16)  [x = bh so per-CU qt mix balances causal work; same-bh blocks
// share an XCD's L2 for K/V]. block 256 = 4 waves, wave owns 32 q-rows. KVBLK=64.
// T14 async-STAGE: issue tile t+1 global->reg loads after barrier2, write them next iter.
__global__ __launch_bounds__(256) void k_attn(
    const unsigned short* __restrict__ q_ws, const unsigned short* __restrict__ k_ws,
    const unsigned short* __restrict__ vt_ws, unsigned short* __restrict__ y_ws) {
  __shared__ __align__(16) unsigned short Ks[64][72];  // K tile [t][d], padded
  __shared__ __align__(16) unsigned short Vs[64][72];  // V^T tile [d][t], padded
  const int bh = blockIdx.x;
  const int q0 = blockIdx.y * 128;
  const int tid = threadIdx.x, w = tid >> 6, l = tid & 63;
  const int lr = l & 15, lg = l >> 4;
  const unsigned short* Qp = q_ws + ((size_t)bh * 2048 + q0 + w * 32) * 64;
  const unsigned short* Kp = k_ws + (size_t)bh * 2048 * 64;
  const unsigned short* Vtp = vt_ws + (size_t)bh * 64 * 2048;
  // Q fragments (B-operand), pre-scaled by 1/sqrt(64)=0.125 (exact in bf16)
  short8 qf[2][2];
#pragma unroll
  for (int i = 0; i < 2; ++i)
#pragma unroll
    for (int ks = 0; ks < 2; ++ks) {
      short8 v = *(const short8*)(Qp + (i * 16 + lr) * 64 + ks * 32 + lg * 8);
#pragma unroll
      for (int e = 0; e < 8; ++e)
        v[e] = (short)f2bf(bf2f((unsigned short)v[e]) * 0.125f);
      qf[i][ks] = v;
    }
  float m_st[2] = {-INFINITY, -INFINITY}, l_st[2] = {0.f, 0.f};
  f32x4 o[2][4] = {};
  const int nt = (q0 >> 6) + 2;  // tiles 0..2*qt+1
  const int qhi = q0 + w * 32 + 31;
  const int srow = (tid * 8) >> 6, scc = (tid * 8) & 63;  // staging coords (rep stride 32 rows)
  // prologue: load tile 0 into regs
  short8 kreg[2], vreg[2];
#pragma unroll
  for (int rep = 0; rep < 2; ++rep) {
    int row = srow + rep * 32;
    kreg[rep] = *(const short8*)(Kp + (size_t)row * 64 + scc);
    vreg[rep] = *(const short8*)(Vtp + (size_t)row * 2048 + scc);
  }
  for (int kt = 0; kt < nt; ++kt) {
    __syncthreads();  // prior tile's LDS reads complete (noop at kt=0)
#pragma unroll
    for (int rep = 0; rep < 2; ++rep) {
      int row = srow + rep * 32;
      *(short8*)&Ks[row][scc] = kreg[rep];
      *(short8*)&Vs[row][scc] = vreg[rep];
    }
    __syncthreads();
    // issue next tile's global loads now; latency hides under compute below
    {
      int ktn = (kt + 1 < nt) ? kt + 1 : kt;
#pragma unroll
      for (int rep = 0; rep < 2; ++rep) {
        int row = srow + rep * 32;
        kreg[rep] = *(const short8*)(Kp + (size_t)(ktn * 64 + row) * 64 + scc);
        vreg[rep] = *(const short8*)(Vtp + (size_t)row * 2048 + ktn * 64 + scc);
      }
    }
    if (kt * 64 > qhi) continue;  // wave-level causal skip (barriers already passed)
    // S^T = K * Q^T : s[j][i] holds S[k = kt*64 + j*16 + lg*4 + r][q = q0+w*32 + i*16 + lr]
    f32x4 s[4][2] = {};
#pragma unroll
    for (int ks = 0; ks < 2; ++ks) {
      short8 kf[4];
#pragma unroll
      for (int j = 0; j < 4; ++j) kf[j] = *(const short8*)&Ks[j * 16 + lr][ks * 32 + lg * 8];
#pragma unroll
      for (int j = 0; j < 4; ++j)
#pragma unroll
        for (int i = 0; i < 2; ++i)
          s[j][i] = __builtin_amdgcn_mfma_f32_16x16x32_bf16(kf[j], qf[i][ks], s[j][i], 0, 0, 0);
    }
    if (kt * 64 + 63 > q0 + w * 32) {  // tile touches the diagonal -> mask
#pragma unroll
      for (int j = 0; j < 4; ++j)
#pragma unroll
        for (int i = 0; i < 2; ++i) {
          int gq = q0 + w * 32 + i * 16 + lr;
          int gk0 = kt * 64 + j * 16 + lg * 4;
#pragma unroll
          for (int r = 0; r < 4; ++r)
            if (gk0 + r > gq) s[j][i][r] = -INFINITY;
        }
    }
    union PaU { unsigned int u[4]; short8 v; };
    PaU pa[2][2];
#pragma unroll
    for (int i = 0; i < 2; ++i) {
      // row q = i*16+lr stats: in-lane fold over 16 + 2 shfl (replicas differ in lg)
      float tm = s[0][i][0];
#pragma unroll
      for (int j = 0; j < 4; ++j)
#pragma unroll
        for (int r = 0; r < 4; ++r) tm = fmaxf(tm, s[j][i][r]);
      tm = fmaxf(tm, __shfl_xor(tm, 16));
      tm = fmaxf(tm, __shfl_xor(tm, 32));
      float nm = fmaxf(m_st[i], tm);
      float corr = __expf(m_st[i] - nm);
      m_st[i] = nm;
      float ts = 0.f;
#pragma unroll
      for (int j = 0; j < 4; ++j)
#pragma unroll
        for (int r = 0; r < 4; ++r) {
          float p = __expf(s[j][i][r] - nm);
          s[j][i][r] = p;
          ts += p;
        }
      ts += __shfl_xor(ts, 16);
      ts += __shfl_xor(ts, 32);
      l_st[i] = l_st[i] * corr + ts;
      // redistribute corr to o-row holders (o rows: q = i*16 + lg*4 + r)
      float co[4];
#pragma unroll
      for (int r = 0; r < 4; ++r) co[r] = __shfl(corr, (l & 48) | (lg * 4 + r));
#pragma unroll
      for (int jd = 0; jd < 4; ++jd)
#pragma unroll
        for (int r = 0; r < 4; ++r) o[i][jd][r] *= co[r];
      // pack P to bf16 pairs: pk[j][h] = {P[k=j*16+lg*4+2h], P[k=..+2h+1]} for q=i*16+lr
      unsigned int pk[4][2];
#pragma unroll
      for (int j = 0; j < 4; ++j)
#pragma unroll
        for (int h = 0; h < 2; ++h)
          pk[j][h] = pack_bf16(s[j][i][2 * h], s[j][i][2 * h + 1]);
      // gather A-operand words: lane needs P[q=i*16+lr][k = ks*32 + lg*8 + 2*wi +{0,1}]
#pragma unroll
      for (int ks = 0; ks < 2; ++ks)
#pragma unroll
        for (int wi = 0; wi < 4; ++wi) {
          int src = ((lg & 1) * 2 + (wi >> 1)) * 16 + lr;
          unsigned int w0 = __shfl(pk[ks * 2][wi & 1], src);
          unsigned int w1 = __shfl(pk[ks * 2 + 1][wi & 1], src);
          pa[i][ks].u[wi] = (lg >> 1) ? w1 : w0;
        }
    }
    // O += P * V  (A = P frags, B = V^T from Vs[d][t])
#pragma unroll
    for (int ks = 0; ks < 2; ++ks) {
      short8 vf[4];
#pragma unroll
      for (int jd = 0; jd < 4; ++jd) vf[jd] = *(const short8*)&Vs[jd * 16 + lr][ks * 32 + lg * 8];
#pragma unroll
      for (int i = 0; i < 2; ++i)
#pragma unroll
        for (int jd = 0; jd < 4; ++jd)
          o[i][jd] = __builtin_amdgcn_mfma_f32_16x16x32_bf16(pa[i][ks].v, vf[jd], o[i][jd], 0, 0, 0);
    }
  }
  // epilogue: o rows q = i*16+lg*4+r, cols d = jd*16+lr
  int b = bh >> 4, h = bh & 15;
#pragma unroll
  for (int i = 0; i < 2; ++i) {
    float li[4];
#pragma unroll
    for (int r = 0; r < 4; ++r)
      li[r] = 1.f / __shfl(l_st[i], (l & 48) | (lg * 4 + r));
#pragma unroll
    for (int r = 0; r < 4; ++r) {
      int grow = q0 + w * 32 + i * 16 + lg * 4 + r;
#pragma unroll
      for (int jd = 0; jd < 4; ++jd)
        y_ws[((size_t)(b * 2048 + grow)) * 1024 + h * 64 + jd * 16 + lr] =
            f2bf(o[i][jd][r] * li[r]);
    }
  }
}

extern "C" void kernel_launch(void* const* d_in, const int* in_sizes, int n_in,
                              void* d_out, int out_size, void* d_ws, size_t ws_size,
                              hipStream_t stream) {
  const float* x      = (const float*)d_in[0];
  const float* w_qkv  = (const float*)d_in[1];
  const float* w_proj = (const float*)d_in[2];
  float* out = (float*)d_out;
  const int Mm = 8192, Cc = 1024;  // B*T, C
  unsigned short* ws     = (unsigned short*)d_ws;
  unsigned short* xb     = ws;                                  // [8192,1024] bf16
  unsigned short* wqkvT  = xb + (size_t)Mm * Cc;                // [3072,1024] bf16
  unsigned short* wprojT = wqkvT + (size_t)3 * Cc * Cc;         // [1024,1024] bf16
  unsigned short* q_ws   = wprojT + (size_t)Cc * Cc;            // [B,H,T,D] bf16
  unsigned short* k_ws   = q_ws + (size_t)Mm * Cc;              // [B,H,T,D] bf16
  unsigned short* vt_ws  = k_ws + (size_t)Mm * Cc;              // [B,H,D,T] bf16 (transposed)
  unsigned short* y_ws   = xb;  // alias: xb dead after GEMM1

  k_convert<<<dim3(Mm * Cc / 8 / 256), 256, 0, stream>>>(x, xb, Mm * Cc);
  k_transpose<<<dim3(3 * Cc / 32, Cc / 32), 256, 0, stream>>>(w_qkv, wqkvT, Cc, 3 * Cc);
  k_transpose<<<dim3(Cc / 32, Cc / 32), 256, 0, stream>>>(w_proj, wprojT, Cc, Cc);
  k_gemm<0><<<dim3(3 * Cc / 128, Mm / 128), 256, 0, stream>>>(
      xb, wqkvT, nullptr, q_ws, k_ws, vt_ws, Mm, 3 * Cc, Cc);
  k_attn<<<dim3(64, 16), 256, 0, stream>>>(q_ws, k_ws, vt_ws, y_ws);
  k_gemm<1><<<dim3(Cc / 128, Mm / 128), 256, 0, stream>>>(
      y_ws, wprojT, out, nullptr, nullptr, nullptr, Mm, Cc, Cc);
}

// Round 9
// 306.580 us; speedup vs baseline: 1.7496x; 1.0162x over previous
//
#include <hip/hip_runtime.h>
#include <hip/hip_bf16.h>
#include <stdint.h>

using short8 = __attribute__((ext_vector_type(8))) short;
using s4vec  = __attribute__((ext_vector_type(4))) short;
using f32x4  = __attribute__((ext_vector_type(4))) float;

__device__ inline unsigned short f2bf(float f) {
  union { float f; unsigned int u; } v; v.f = f;
  unsigned int r = v.u + 0x7FFFu + ((v.u >> 16) & 1u);
  return (unsigned short)(r >> 16);
}
__device__ inline float bf2f(unsigned short u) {
  union { unsigned int u; float f; } v; v.u = ((unsigned int)u) << 16;
  return v.f;
}
__device__ inline unsigned int pack_bf16(float lo, float hi) {
  union { __hip_bfloat162 b; unsigned int u; } cv;
  cv.b = __float22bfloat162_rn(make_float2(lo, hi));  // .x -> low 16 bits
  return cv.u;
}

#if __has_builtin(__builtin_amdgcn_global_load_lds)
#define HAVE_GLOAD_LDS 1
// CK-style: global (AS1) per-lane src, wave-uniform LDS (AS3) base; HW writes base+lane*16.
__device__ inline void gload_lds16(const unsigned short* g, unsigned short* l) {
  auto gp = (const __attribute__((address_space(1))) unsigned int*)(uintptr_t)g;
  auto lp = (__attribute__((address_space(3))) unsigned int*)(uintptr_t)l;
  __builtin_amdgcn_global_load_lds(gp, lp, 16, 0, 0);
}
#else
#define HAVE_GLOAD_LDS 0
#endif

// ---------------- elementwise f32 -> bf16 ----------------
__global__ __launch_bounds__(256) void k_convert(const float* __restrict__ in,
                                                 unsigned short* __restrict__ out, int n) {
  int i = (blockIdx.x * 256 + threadIdx.x) * 8;
  if (i >= n) return;
  float4 a = *(const float4*)(in + i);
  float4 b = *(const float4*)(in + i + 4);
  short8 o;
  o[0] = (short)f2bf(a.x); o[1] = (short)f2bf(a.y);
  o[2] = (short)f2bf(a.z); o[3] = (short)f2bf(a.w);
  o[4] = (short)f2bf(b.x); o[5] = (short)f2bf(b.y);
  o[6] = (short)f2bf(b.z); o[7] = (short)f2bf(b.w);
  *(short8*)(out + i) = o;
}

// ---------------- transpose-convert: in[R][C] f32 -> out[C][R] bf16 ----------------
__global__ __launch_bounds__(256) void k_transpose(const float* __restrict__ in,
                                                   unsigned short* __restrict__ out,
                                                   int R, int C) {
  __shared__ float t[32][33];
  int c0 = blockIdx.x * 32, r0 = blockIdx.y * 32;
  int cl = threadIdx.x & 31, rl = threadIdx.x >> 5;  // rl 0..7
  for (int p = 0; p < 4; ++p)
    t[rl + p * 8][cl] = in[(size_t)(r0 + rl + p * 8) * C + c0 + cl];
  __syncthreads();
  for (int p = 0; p < 4; ++p)
    out[(size_t)(c0 + rl + p * 8) * R + r0 + cl] = f2bf(t[cl][rl + p * 8]);
}

// ---------------- bf16 GEMM (m97 structure): C[M,N] = A[M,K] * Bt[N,K]^T ----------------
// Unpadded [128][32] LDS tiles staged via global_load_lds width-16.
// MODE 0: scatter epilogue into q/k ws [B,H,T,D] and v ws [B,H,D,T] (V transposed)
// MODE 1: plain fp32 C write
template <int MODE>
__global__ __launch_bounds__(256) void k_gemm(
    const unsigned short* __restrict__ A, const unsigned short* __restrict__ Bt,
    float* __restrict__ Cf,
    unsigned short* __restrict__ q_ws, unsigned short* __restrict__ k_ws,
    unsigned short* __restrict__ v_ws, int M, int N, int K) {
  __shared__ __align__(16) unsigned short As[128][32];
  __shared__ __align__(16) unsigned short Bs[128][32];
  const int tid = threadIdx.x;
  const int w = tid >> 6, l = tid & 63;
  const int lr = l & 15, lg = l >> 4;
  const int wr = w >> 1, wc = w & 1;
  const int m0 = blockIdx.y * 128, n0 = blockIdx.x * 128;
  f32x4 acc[4][4] = {};
  for (int k0 = 0; k0 < K; k0 += 32) {
#pragma unroll
    for (int rep = 0; rep < 2; ++rep) {
      int e = rep * 2048 + tid * 8;  // flat short index; row = e>>5, kk = e&31
      int row = e >> 5, kk = e & 31;
      const unsigned short* ga = A + (size_t)(m0 + row) * K + k0 + kk;
      const unsigned short* gb = Bt + (size_t)(n0 + row) * K + k0 + kk;
#if HAVE_GLOAD_LDS
      // wave-uniform LDS base (shorts): rep*2048 + w*512; lane writes base + lane*16B
      unsigned short* la = &As[0][0] + rep * 2048 + w * 512;
      unsigned short* lb = &Bs[0][0] + rep * 2048 + w * 512;
      gload_lds16(ga, la);
      gload_lds16(gb, lb);
#else
      *(short8*)&As[row][kk] = *(const short8*)ga;
      *(short8*)&Bs[row][kk] = *(const short8*)gb;
#endif
    }
    __syncthreads();
    short8 af[4], bf[4];
#pragma unroll
    for (int i = 0; i < 4; ++i) af[i] = *(const short8*)&As[wr * 64 + i * 16 + lr][lg * 8];
#pragma unroll
    for (int j = 0; j < 4; ++j) bf[j] = *(const short8*)&Bs[wc * 64 + j * 16 + lr][lg * 8];
#pragma unroll
    for (int i = 0; i < 4; ++i)
#pragma unroll
      for (int j = 0; j < 4; ++j)
        acc[i][j] = __builtin_amdgcn_mfma_f32_16x16x32_bf16(af[i], bf[j], acc[i][j], 0, 0, 0);
    __syncthreads();
  }
  // C/D layout: col = lane&15, row = (lane>>4)*4 + reg
  if constexpr (MODE == 1) {
#pragma unroll
    for (int i = 0; i < 4; ++i)
#pragma unroll
      for (int j = 0; j < 4; ++j)
#pragma unroll
        for (int r = 0; r < 4; ++r) {
          int row = m0 + wr * 64 + i * 16 + lg * 4 + r;
          int col = n0 + wc * 64 + j * 16 + lr;
          Cf[(size_t)row * N + col] = acc[i][j][r];
        }
  } else {
#pragma unroll
    for (int i = 0; i < 4; ++i)
#pragma unroll
      for (int j = 0; j < 4; ++j) {
        int row0 = m0 + wr * 64 + i * 16 + lg * 4;
        int col = n0 + wc * 64 + j * 16 + lr;
        int b = row0 >> 11, t = row0 & 2047;
        int sect = col >> 10, c = col & 1023;
        int h = c >> 6, d = c & 63;
        if (sect == 2) {
          s4vec pv;
#pragma unroll
          for (int r = 0; r < 4; ++r) pv[r] = (short)f2bf(acc[i][j][r]);
          *(s4vec*)(v_ws + (((size_t)(b * 16 + h)) * 64 + d) * 2048 + t) = pv;
        } else {
          unsigned short* dst = (sect == 0) ? q_ws : k_ws;
#pragma unroll
          for (int r = 0; r < 4; ++r)
            dst[(((size_t)(b * 16 + h)) * 2048 + t + r) * 64 + d] = f2bf(acc[i][j][r]);
        }
      }
  }
}

// ---------------- causal flash attention, swapped-QK^T, in-register softmax ----------------
// grid: (bh=64, qt=16); block 256 = 4 waves, wave owns 32 q-rows. KVBLK=64.
// This round: O^T PV (o = mfma(V^T, P^T)) -> corr/l lane-local, vectorized epilogue;
// T13 defer-max (skip rescale when __all(tm <= m+8)).
__global__ __launch_bounds__(256) void k_attn(
    const unsigned short* __restrict__ q_ws, const unsigned short* __restrict__ k_ws,
    const unsigned short* __restrict__ vt_ws, unsigned short* __restrict__ y_ws) {
  __shared__ __align__(16) unsigned short Ks[64][72];  // K tile [t][d], padded
  __shared__ __align__(16) unsigned short Vs[64][72];  // V^T tile [d][t], padded
  const int bh = blockIdx.x;
  const int q0 = blockIdx.y * 128;
  const int tid = threadIdx.x, w = tid >> 6, l = tid & 63;
  const int lr = l & 15, lg = l >> 4;
  const unsigned short* Qp = q_ws + ((size_t)bh * 2048 + q0 + w * 32) * 64;
  const unsigned short* Kp = k_ws + (size_t)bh * 2048 * 64;
  const unsigned short* Vtp = vt_ws + (size_t)bh * 64 * 2048;
  // Q fragments (B-operand), pre-scaled by 1/sqrt(64)=0.125 (exact in bf16)
  short8 qf[2][2];
#pragma unroll
  for (int i = 0; i < 2; ++i)
#pragma unroll
    for (int ks = 0; ks < 2; ++ks) {
      short8 v = *(const short8*)(Qp + (i * 16 + lr) * 64 + ks * 32 + lg * 8);
#pragma unroll
      for (int e = 0; e < 8; ++e)
        v[e] = (short)f2bf(bf2f((unsigned short)v[e]) * 0.125f);
      qf[i][ks] = v;
    }
  float m_st[2] = {-INFINITY, -INFINITY}, l_st[2] = {0.f, 0.f};
  f32x4 o[2][4] = {};  // O^T: rows d = jd*16+lg*4+r, cols q = i*16+lr
  const int nt = (q0 >> 6) + 2;  // tiles 0..2*qt+1
  const int qhi = q0 + w * 32 + 31;
  const int srow = (tid * 8) >> 6, scc = (tid * 8) & 63;  // staging coords (rep stride 32 rows)
  // prologue: load tile 0 into regs
  short8 kreg[2], vreg[2];
#pragma unroll
  for (int rep = 0; rep < 2; ++rep) {
    int row = srow + rep * 32;
    kreg[rep] = *(const short8*)(Kp + (size_t)row * 64 + scc);
    vreg[rep] = *(const short8*)(Vtp + (size_t)row * 2048 + scc);
  }
  for (int kt = 0; kt < nt; ++kt) {
    __syncthreads();  // prior tile's LDS reads complete (noop at kt=0)
#pragma unroll
    for (int rep = 0; rep < 2; ++rep) {
      int row = srow + rep * 32;
      *(short8*)&Ks[row][scc] = kreg[rep];
      *(short8*)&Vs[row][scc] = vreg[rep];
    }
    __syncthreads();
    // issue next tile's global loads now; latency hides under compute below
    {
      int ktn = (kt + 1 < nt) ? kt + 1 : kt;
#pragma unroll
      for (int rep = 0; rep < 2; ++rep) {
        int row = srow + rep * 32;
        kreg[rep] = *(const short8*)(Kp + (size_t)(ktn * 64 + row) * 64 + scc);
        vreg[rep] = *(const short8*)(Vtp + (size_t)row * 2048 + ktn * 64 + scc);
      }
    }
    if (kt * 64 > qhi) continue;  // wave-level causal skip (barriers already passed)
    // S^T = K * Q^T : s[j][i] holds S[k = kt*64 + j*16 + lg*4 + r][q = q0+w*32 + i*16 + lr]
    f32x4 s[4][2] = {};
#pragma unroll
    for (int ks = 0; ks < 2; ++ks) {
      short8 kf[4];
#pragma unroll
      for (int j = 0; j < 4; ++j) kf[j] = *(const short8*)&Ks[j * 16 + lr][ks * 32 + lg * 8];
#pragma unroll
      for (int j = 0; j < 4; ++j)
#pragma unroll
        for (int i = 0; i < 2; ++i)
          s[j][i] = __builtin_amdgcn_mfma_f32_16x16x32_bf16(kf[j], qf[i][ks], s[j][i], 0, 0, 0);
    }
    if (kt * 64 + 63 > q0 + w * 32) {  // tile touches the diagonal -> mask
#pragma unroll
      for (int j = 0; j < 4; ++j)
#pragma unroll
        for (int i = 0; i < 2; ++i) {
          int gq = q0 + w * 32 + i * 16 + lr;
          int gk0 = kt * 64 + j * 16 + lg * 4;
#pragma unroll
          for (int r = 0; r < 4; ++r)
            if (gk0 + r > gq) s[j][i][r] = -INFINITY;
        }
    }
    union PaU { unsigned int u[4]; short8 v; };
    PaU pa[2][2];
#pragma unroll
    for (int i = 0; i < 2; ++i) {
      // row q = i*16+lr max: in-lane fold over 16 + 2 shfl (replicas differ in lg)
      float tm = s[0][i][0];
#pragma unroll
      for (int j = 0; j < 4; ++j)
#pragma unroll
        for (int r = 0; r < 4; ++r) tm = fmaxf(tm, s[j][i][r]);
      tm = fmaxf(tm, __shfl_xor(tm, 16));
      tm = fmaxf(tm, __shfl_xor(tm, 32));
      // T13 defer-max: only rescale when some row grew its max by >8
      if (!__all(tm <= m_st[i] + 8.f)) {
        float nm = fmaxf(m_st[i], tm);
        float corr = __expf(m_st[i] - nm);
        m_st[i] = nm;
        l_st[i] *= corr;
        // O^T cols are q = lr -> corr applies lane-locally, no gather
#pragma unroll
        for (int jd = 0; jd < 4; ++jd)
#pragma unroll
          for (int r = 0; r < 4; ++r) o[i][jd][r] *= corr;
      }
      float ts = 0.f;
#pragma unroll
      for (int j = 0; j < 4; ++j)
#pragma unroll
        for (int r = 0; r < 4; ++r) {
          float p = __expf(s[j][i][r] - m_st[i]);
          s[j][i][r] = p;
          ts += p;
        }
      ts += __shfl_xor(ts, 16);
      ts += __shfl_xor(ts, 32);
      l_st[i] += ts;
      // pack P to bf16 pairs: pk[j][h] = {P[k=j*16+lg*4+2h], P[k=..+2h+1]} for q=i*16+lr
      unsigned int pk[4][2];
#pragma unroll
      for (int j = 0; j < 4; ++j)
#pragma unroll
        for (int h = 0; h < 2; ++h)
          pk[j][h] = pack_bf16(s[j][i][2 * h], s[j][i][2 * h + 1]);
      // gather operand words: lane needs P[q=i*16+lr][k = ks*32 + lg*8 + 2*wi +{0,1}]
      // (fragment layout identical for A and B: outer=lr, contraction=lg*8+e)
#pragma unroll
      for (int ks = 0; ks < 2; ++ks)
#pragma unroll
        for (int wi = 0; wi < 4; ++wi) {
          int src = ((lg & 1) * 2 + (wi >> 1)) * 16 + lr;
          unsigned int w0 = __shfl(pk[ks * 2][wi & 1], src);
          unsigned int w1 = __shfl(pk[ks * 2 + 1][wi & 1], src);
          pa[i][ks].u[wi] = (lg >> 1) ? w1 : w0;
        }
    }
    // O^T += V^T * P^T  (A = V^T frags from Vs[d][t], B = P^T frags = pa)
#pragma unroll
    for (int ks = 0; ks < 2; ++ks) {
      short8 vf[4];
#pragma unroll
      for (int jd = 0; jd < 4; ++jd) vf[jd] = *(const short8*)&Vs[jd * 16 + lr][ks * 32 + lg * 8];
#pragma unroll
      for (int i = 0; i < 2; ++i)
#pragma unroll
        for (int jd = 0; jd < 4; ++jd)
          o[i][jd] = __builtin_amdgcn_mfma_f32_16x16x32_bf16(vf[jd], pa[i][ks].v, o[i][jd], 0, 0, 0);
    }
  }
  // epilogue: O^T -> y[b, t=q0+w*32+i*16+lr, h*64 + jd*16 + lg*4 + r]; 8B vector stores
  int b = bh >> 4, h = bh & 15;
#pragma unroll
  for (int i = 0; i < 2; ++i) {
    float li = 1.f / l_st[i];
    int t = q0 + w * 32 + i * 16 + lr;
#pragma unroll
    for (int jd = 0; jd < 4; ++jd) {
      s4vec pv;
#pragma unroll
      for (int r = 0; r < 4; ++r) pv[r] = (short)f2bf(o[i][jd][r] * li);
      *(s4vec*)(y_ws + ((size_t)(b * 2048 + t)) * 1024 + h * 64 + jd * 16 + lg * 4) = pv;
    }
  }
}

extern "C" void kernel_launch(void* const* d_in, const int* in_sizes, int n_in,
                              void* d_out, int out_size, void* d_ws, size_t ws_size,
                              hipStream_t stream) {
  const float* x      = (const float*)d_in[0];
  const float* w_qkv  = (const float*)d_in[1];
  const float* w_proj = (const float*)d_in[2];
  float* out = (float*)d_out;
  const int Mm = 8192, Cc = 1024;  // B*T, C
  unsigned short* ws     = (unsigned short*)d_ws;
  unsigned short* xb     = ws;                                  // [8192,1024] bf16
  unsigned short* wqkvT  = xb + (size_t)Mm * Cc;                // [3072,1024] bf16
  unsigned short* wprojT = wqkvT + (size_t)3 * Cc * Cc;         // [1024,1024] bf16
  unsigned short* q_ws   = wprojT + (size_t)Cc * Cc;            // [B,H,T,D] bf16
  unsigned short* k_ws   = q_ws + (size_t)Mm * Cc;              // [B,H,T,D] bf16
  unsigned short* vt_ws  = k_ws + (size_t)Mm * Cc;              // [B,H,D,T] bf16 (transposed)
  unsigned short* y_ws   = xb;  // alias: xb dead after GEMM1

  k_convert<<<dim3(Mm * Cc / 8 / 256), 256, 0, stream>>>(x, xb, Mm * Cc);
  k_transpose<<<dim3(3 * Cc / 32, Cc / 32), 256, 0, stream>>>(w_qkv, wqkvT, Cc, 3 * Cc);
  k_transpose<<<dim3(Cc / 32, Cc / 32), 256, 0, stream>>>(w_proj, wprojT, Cc, Cc);
  k_gemm<0><<<dim3(3 * Cc / 128, Mm / 128), 256, 0, stream>>>(
      xb, wqkvT, nullptr, q_ws, k_ws, vt_ws, Mm, 3 * Cc, Cc);
  k_attn<<<dim3(64, 16), 256, 0, stream>>>(q_ws, k_ws, vt_ws, y_ws);
  k_gemm<1><<<dim3(Cc / 128, Mm / 128), 256, 0, stream>>>(
      y_ws, wprojT, out, nullptr, nullptr, nullptr, Mm, Cc, Cc);
}

// Round 11
// 291.564 us; speedup vs baseline: 1.8397x; 1.0515x over previous
//
#include <hip/hip_runtime.h>
#include <hip/hip_bf16.h>
#include <stdint.h>

using short8 = __attribute__((ext_vector_type(8))) short;
using s4vec  = __attribute__((ext_vector_type(4))) short;
using f32x4  = __attribute__((ext_vector_type(4))) float;
using u32x2  = __attribute__((ext_vector_type(2))) unsigned int;
using u32x4  = __attribute__((ext_vector_type(4))) unsigned int;

__device__ inline unsigned short f2bf(float f) {
  union { float f; unsigned int u; } v; v.f = f;
  unsigned int r = v.u + 0x7FFFu + ((v.u >> 16) & 1u);
  return (unsigned short)(r >> 16);
}
__device__ inline float bf2f(unsigned short u) {
  union { unsigned int u; float f; } v; v.u = ((unsigned int)u) << 16;
  return v.f;
}
__device__ inline unsigned int pack_bf16(float lo, float hi) {
  union { __hip_bfloat162 b; unsigned int u; } cv;
  cv.b = __float22bfloat162_rn(make_float2(lo, hi));  // .x -> low 16 bits
  return cv.u;
}

#if __has_builtin(__builtin_amdgcn_global_load_lds)
#define HAVE_GLOAD_LDS 1
// CK-style: global (AS1) per-lane src, wave-uniform LDS (AS3) base; HW writes base+lane*16.
__device__ inline void gload_lds16(const unsigned short* g, unsigned short* l) {
  auto gp = (const __attribute__((address_space(1))) unsigned int*)(uintptr_t)g;
  auto lp = (__attribute__((address_space(3))) unsigned int*)(uintptr_t)l;
  __builtin_amdgcn_global_load_lds(gp, lp, 16, 0, 0);
}
#else
#define HAVE_GLOAD_LDS 0
#endif

// ---------------- elementwise f32 -> bf16 ----------------
__global__ __launch_bounds__(256) void k_convert(const float* __restrict__ in,
                                                 unsigned short* __restrict__ out, int n) {
  int i = (blockIdx.x * 256 + threadIdx.x) * 8;
  if (i >= n) return;
  float4 a = *(const float4*)(in + i);
  float4 b = *(const float4*)(in + i + 4);
  short8 o;
  o[0] = (short)f2bf(a.x); o[1] = (short)f2bf(a.y);
  o[2] = (short)f2bf(a.z); o[3] = (short)f2bf(a.w);
  o[4] = (short)f2bf(b.x); o[5] = (short)f2bf(b.y);
  o[6] = (short)f2bf(b.z); o[7] = (short)f2bf(b.w);
  *(short8*)(out + i) = o;
}

// ---------------- transpose-convert: in[R][C] f32 -> out[C][R] bf16 ----------------
__global__ __launch_bounds__(256) void k_transpose(const float* __restrict__ in,
                                                   unsigned short* __restrict__ out,
                                                   int R, int C) {
  __shared__ float t[32][33];
  int c0 = blockIdx.x * 32, r0 = blockIdx.y * 32;
  int cl = threadIdx.x & 31, rl = threadIdx.x >> 5;  // rl 0..7
  for (int p = 0; p < 4; ++p)
    t[rl + p * 8][cl] = in[(size_t)(r0 + rl + p * 8) * C + c0 + cl];
  __syncthreads();
  for (int p = 0; p < 4; ++p)
    out[(size_t)(c0 + rl + p * 8) * R + r0 + cl] = f2bf(t[cl][rl + p * 8]);
}

// ---------------- bf16 GEMM (m97 structure): C[M,N] = A[M,K] * Bt[N,K]^T ----------------
// Unpadded [128][32] LDS tiles staged via global_load_lds width-16.
// MODE 0: scatter epilogue into q/k ws [B,H,T,D] and v ws [B,H,D,T] (V transposed)
// MODE 1: plain fp32 C write
template <int MODE>
__global__ __launch_bounds__(256) void k_gemm(
    const unsigned short* __restrict__ A, const unsigned short* __restrict__ Bt,
    float* __restrict__ Cf,
    unsigned short* __restrict__ q_ws, unsigned short* __restrict__ k_ws,
    unsigned short* __restrict__ v_ws, int M, int N, int K) {
  __shared__ __align__(16) unsigned short As[128][32];
  __shared__ __align__(16) unsigned short Bs[128][32];
  const int tid = threadIdx.x;
  const int w = tid >> 6, l = tid & 63;
  const int lr = l & 15, lg = l >> 4;
  const int wr = w >> 1, wc = w & 1;
  const int m0 = blockIdx.y * 128, n0 = blockIdx.x * 128;
  f32x4 acc[4][4] = {};
  for (int k0 = 0; k0 < K; k0 += 32) {
#pragma unroll
    for (int rep = 0; rep < 2; ++rep) {
      int e = rep * 2048 + tid * 8;  // flat short index; row = e>>5, kk = e&31
      int row = e >> 5, kk = e & 31;
      const unsigned short* ga = A + (size_t)(m0 + row) * K + k0 + kk;
      const unsigned short* gb = Bt + (size_t)(n0 + row) * K + k0 + kk;
#if HAVE_GLOAD_LDS
      // wave-uniform LDS base (shorts): rep*2048 + w*512; lane writes base + lane*16B
      unsigned short* la = &As[0][0] + rep * 2048 + w * 512;
      unsigned short* lb = &Bs[0][0] + rep * 2048 + w * 512;
      gload_lds16(ga, la);
      gload_lds16(gb, lb);
#else
      *(short8*)&As[row][kk] = *(const short8*)ga;
      *(short8*)&Bs[row][kk] = *(const short8*)gb;
#endif
    }
    __syncthreads();
    short8 af[4], bf[4];
#pragma unroll
    for (int i = 0; i < 4; ++i) af[i] = *(const short8*)&As[wr * 64 + i * 16 + lr][lg * 8];
#pragma unroll
    for (int j = 0; j < 4; ++j) bf[j] = *(const short8*)&Bs[wc * 64 + j * 16 + lr][lg * 8];
#pragma unroll
    for (int i = 0; i < 4; ++i)
#pragma unroll
      for (int j = 0; j < 4; ++j)
        acc[i][j] = __builtin_amdgcn_mfma_f32_16x16x32_bf16(af[i], bf[j], acc[i][j], 0, 0, 0);
    __syncthreads();
  }
  // C/D layout: col = lane&15, row = (lane>>4)*4 + reg
  if constexpr (MODE == 1) {
#pragma unroll
    for (int i = 0; i < 4; ++i)
#pragma unroll
      for (int j = 0; j < 4; ++j)
#pragma unroll
        for (int r = 0; r < 4; ++r) {
          int row = m0 + wr * 64 + i * 16 + lg * 4 + r;
          int col = n0 + wc * 64 + j * 16 + lr;
          Cf[(size_t)row * N + col] = acc[i][j][r];
        }
  } else {
#pragma unroll
    for (int i = 0; i < 4; ++i)
#pragma unroll
      for (int j = 0; j < 4; ++j) {
        int row0 = m0 + wr * 64 + i * 16 + lg * 4;
        int col = n0 + wc * 64 + j * 16 + lr;
        int b = row0 >> 11, t = row0 & 2047;
        int sect = col >> 10, c = col & 1023;
        int h = c >> 6, d = c & 63;
        if (sect == 2) {
          s4vec pv;
#pragma unroll
          for (int r = 0; r < 4; ++r) pv[r] = (short)f2bf(acc[i][j][r]);
          *(s4vec*)(v_ws + (((size_t)(b * 16 + h)) * 64 + d) * 2048 + t) = pv;
        } else {
          unsigned short* dst = (sect == 0) ? q_ws : k_ws;
#pragma unroll
          for (int r = 0; r < 4; ++r)
            dst[(((size_t)(b * 16 + h)) * 2048 + t + r) * 64 + d] = f2bf(acc[i][j][r]);
        }
      }
  }
}

// ---------------- causal flash attention, swapped-QK^T, in-register softmax ----------------
// grid: (bh=64, qt=16); block 256 = 4 waves, wave owns 32 q-rows. KVBLK=64.
// This round: (a) P round-trip via per-wave swizzled LDS (replaces 32 bpermute + 16
// cndmask per tile with 8 ds_write_b64 + 4 ds_read_b128, no barrier needed);
// (b) Ks/Vs XOR-swizzled unpadded [64][64] (16B col-block ^= row&7) for optimal
// b128 bank spread on staging writes and fragment reads.
__global__ __launch_bounds__(256) void k_attn(
    const unsigned short* __restrict__ q_ws, const unsigned short* __restrict__ k_ws,
    const unsigned short* __restrict__ vt_ws, unsigned short* __restrict__ y_ws) {
  __shared__ __align__(16) unsigned short Ks[64][64];  // K tile [t][d], XOR-swizzled
  __shared__ __align__(16) unsigned short Vs[64][64];  // V^T tile [d][t], XOR-swizzled
  __shared__ __align__(16) unsigned int   Ps[4][32][32];  // per-wave P [q][k-word], XOR-swz
  const int bh = blockIdx.x;
  const int q0 = blockIdx.y * 128;
  const int tid = threadIdx.x, w = tid >> 6, l = tid & 63;
  const int lr = l & 15, lg = l >> 4;
  const unsigned short* Qp = q_ws + ((size_t)bh * 2048 + q0 + w * 32) * 64;
  const unsigned short* Kp = k_ws + (size_t)bh * 2048 * 64;
  const unsigned short* Vtp = vt_ws + (size_t)bh * 64 * 2048;
  // Q fragments (B-operand), pre-scaled by 1/sqrt(64)=0.125 (exact in bf16)
  short8 qf[2][2];
#pragma unroll
  for (int i = 0; i < 2; ++i)
#pragma unroll
    for (int ks = 0; ks < 2; ++ks) {
      short8 v = *(const short8*)(Qp + (i * 16 + lr) * 64 + ks * 32 + lg * 8);
#pragma unroll
      for (int e = 0; e < 8; ++e)
        v[e] = (short)f2bf(bf2f((unsigned short)v[e]) * 0.125f);
      qf[i][ks] = v;
    }
  float m_st[2] = {-INFINITY, -INFINITY}, l_st[2] = {0.f, 0.f};
  f32x4 o[2][4] = {};  // O^T: rows d = jd*16+lg*4+r, cols q = i*16+lr
  const int nt = (q0 >> 6) + 2;  // tiles 0..2*qt+1
  const int qhi = q0 + w * 32 + 31;
  // staging coords: row = srow + rep*32, 16B col-block cbl, swizzled by row&7 (= srow&7)
  const int srow = tid >> 3, cbl = tid & 7;
  const int scc = cbl * 8;                       // global source col (shorts)
  const int scw = ((cbl ^ (srow & 7)) * 8);      // swizzled LDS col (shorts)
  // fragment-read swizzled cols (16B units): cb' = (ks*4+lg) ^ (lr&7)
  const int fc0 = ((0 * 4 + lg) ^ (lr & 7)) * 8; // ks=0
  const int fc1 = ((1 * 4 + lg) ^ (lr & 7)) * 8; // ks=1
  // prologue: load tile 0 into regs
  short8 kreg[2], vreg[2];
#pragma unroll
  for (int rep = 0; rep < 2; ++rep) {
    int row = srow + rep * 32;
    kreg[rep] = *(const short8*)(Kp + (size_t)row * 64 + scc);
    vreg[rep] = *(const short8*)(Vtp + (size_t)row * 2048 + scc);
  }
  for (int kt = 0; kt < nt; ++kt) {
    __syncthreads();  // prior tile's LDS reads complete (noop at kt=0)
#pragma unroll
    for (int rep = 0; rep < 2; ++rep) {
      int row = srow + rep * 32;
      *(short8*)&Ks[row][scw] = kreg[rep];
      *(short8*)&Vs[row][scw] = vreg[rep];
    }
    __syncthreads();
    // issue next tile's global loads now; latency hides under compute below
    {
      int ktn = (kt + 1 < nt) ? kt + 1 : kt;
#pragma unroll
      for (int rep = 0; rep < 2; ++rep) {
        int row = srow + rep * 32;
        kreg[rep] = *(const short8*)(Kp + (size_t)(ktn * 64 + row) * 64 + scc);
        vreg[rep] = *(const short8*)(Vtp + (size_t)row * 2048 + ktn * 64 + scc);
      }
    }
    if (kt * 64 > qhi) continue;  // wave-level causal skip (barriers already passed)
    // S^T = K * Q^T : s[j][i] holds S[k = kt*64 + j*16 + lg*4 + r][q = q0+w*32 + i*16 + lr]
    f32x4 s[4][2] = {};
#pragma unroll
    for (int ks = 0; ks < 2; ++ks) {
      int fc = ks ? fc1 : fc0;
      short8 kf[4];
#pragma unroll
      for (int j = 0; j < 4; ++j) kf[j] = *(const short8*)&Ks[j * 16 + lr][fc];
#pragma unroll
      for (int j = 0; j < 4; ++j)
#pragma unroll
        for (int i = 0; i < 2; ++i)
          s[j][i] = __builtin_amdgcn_mfma_f32_16x16x32_bf16(kf[j], qf[i][ks], s[j][i], 0, 0, 0);
    }
    if (kt * 64 + 63 > q0 + w * 32) {  // tile touches the diagonal -> mask
#pragma unroll
      for (int j = 0; j < 4; ++j)
#pragma unroll
        for (int i = 0; i < 2; ++i) {
          int gq = q0 + w * 32 + i * 16 + lr;
          int gk0 = kt * 64 + j * 16 + lg * 4;
#pragma unroll
          for (int r = 0; r < 4; ++r)
            if (gk0 + r > gq) s[j][i][r] = -INFINITY;
        }
    }
    union U4S8 { u32x4 u; short8 s; };
    short8 pa[2][2];
#pragma unroll
    for (int i = 0; i < 2; ++i) {
      // row q = i*16+lr max: in-lane fold over 16 + 2 shfl (replicas differ in lg)
      float tm = s[0][i][0];
#pragma unroll
      for (int j = 0; j < 4; ++j)
#pragma unroll
        for (int r = 0; r < 4; ++r) tm = fmaxf(tm, s[j][i][r]);
      tm = fmaxf(tm, __shfl_xor(tm, 16));
      tm = fmaxf(tm, __shfl_xor(tm, 32));
      // T13 defer-max: only rescale when some row grew its max by >8
      if (!__all(tm <= m_st[i] + 8.f)) {
        float nm = fmaxf(m_st[i], tm);
        float corr = __expf(m_st[i] - nm);
        m_st[i] = nm;
        l_st[i] *= corr;
        // O^T cols are q = lr -> corr applies lane-locally, no gather
#pragma unroll
        for (int jd = 0; jd < 4; ++jd)
#pragma unroll
          for (int r = 0; r < 4; ++r) o[i][jd][r] *= corr;
      }
      float ts = 0.f;
#pragma unroll
      for (int j = 0; j < 4; ++j)
#pragma unroll
        for (int r = 0; r < 4; ++r) {
          float p = __expf(s[j][i][r] - m_st[i]);
          s[j][i][r] = p;
          ts += p;
        }
      ts += __shfl_xor(ts, 16);
      ts += __shfl_xor(ts, 32);
      l_st[i] += ts;
      // P -> per-wave LDS (bf16 packed), XOR-swizzled u64 units: u = (j*4+lg) ^ (lr&14)
      unsigned int* prow = &Ps[w][i * 16 + lr][0];
#pragma unroll
      for (int j = 0; j < 4; ++j) {
        u32x2 v2;
        v2[0] = pack_bf16(s[j][i][0], s[j][i][1]);
        v2[1] = pack_bf16(s[j][i][2], s[j][i][3]);
        *(u32x2*)(prow + (((j * 4 + lg) ^ (lr & 14)) * 2)) = v2;
      }
      // read back operand fragments: b128 at u64 pair base (ks*8+lg*2) ^ (lr&14) (even)
#pragma unroll
      for (int ks = 0; ks < 2; ++ks) {
        U4S8 cv;
        cv.u = *(const u32x4*)(prow + (((ks * 8 + lg * 2) ^ (lr & 14)) * 2));
        pa[i][ks] = cv.s;
      }
    }
    // O^T += V^T * P^T  (A = V^T frags from Vs, B = P^T frags = pa)
#pragma unroll
    for (int ks = 0; ks < 2; ++ks) {
      int fc = ks ? fc1 : fc0;
      short8 vf[4];
#pragma unroll
      for (int jd = 0; jd < 4; ++jd) vf[jd] = *(const short8*)&Vs[jd * 16 + lr][fc];
#pragma unroll
      for (int i = 0; i < 2; ++i)
#pragma unroll
        for (int jd = 0; jd < 4; ++jd)
          o[i][jd] = __builtin_amdgcn_mfma_f32_16x16x32_bf16(vf[jd], pa[i][ks], o[i][jd], 0, 0, 0);
    }
  }
  // epilogue: O^T -> y[b, t=q0+w*32+i*16+lr, h*64 + jd*16 + lg*4 + r]; 8B vector stores
  int b = bh >> 4, h = bh & 15;
#pragma unroll
  for (int i = 0; i < 2; ++i) {
    float li = 1.f / l_st[i];
    int t = q0 + w * 32 + i * 16 + lr;
#pragma unroll
    for (int jd = 0; jd < 4; ++jd) {
      s4vec pv;
#pragma unroll
      for (int r = 0; r < 4; ++r) pv[r] = (short)f2bf(o[i][jd][r] * li);
      *(s4vec*)(y_ws + ((size_t)(b * 2048 + t)) * 1024 + h * 64 + jd * 16 + lg * 4) = pv;
    }
  }
}

extern "C" void kernel_launch(void* const* d_in, const int* in_sizes, int n_in,
                              void* d_out, int out_size, void* d_ws, size_t ws_size,
                              hipStream_t stream) {
  const float* x      = (const float*)d_in[0];
  const float* w_qkv  = (const float*)d_in[1];
  const float* w_proj = (const float*)d_in[2];
  float* out = (float*)d_out;
  const int Mm = 8192, Cc = 1024;  // B*T, C
  unsigned short* ws     = (unsigned short*)d_ws;
  unsigned short* xb     = ws;                                  // [8192,1024] bf16
  unsigned short* wqkvT  = xb + (size_t)Mm * Cc;                // [3072,1024] bf16
  unsigned short* wprojT = wqkvT + (size_t)3 * Cc * Cc;         // [1024,1024] bf16
  unsigned short* q_ws   = wprojT + (size_t)Cc * Cc;            // [B,H,T,D] bf16
  unsigned short* k_ws   = q_ws + (size_t)Mm * Cc;              // [B,H,T,D] bf16
  unsigned short* vt_ws  = k_ws + (size_t)Mm * Cc;              // [B,H,D,T] bf16 (transposed)
  unsigned short* y_ws   = xb;  // alias: xb dead after GEMM1

  k_convert<<<dim3(Mm * Cc / 8 / 256), 256, 0, stream>>>(x, xb, Mm * Cc);
  k_transpose<<<dim3(3 * Cc / 32, Cc / 32), 256, 0, stream>>>(w_qkv, wqkvT, Cc, 3 * Cc);
  k_transpose<<<dim3(Cc / 32, Cc / 32), 256, 0, stream>>>(w_proj, wprojT, Cc, Cc);
  k_gemm<0><<<dim3(3 * Cc / 128, Mm / 128), 256, 0, stream>>>(
      xb, wqkvT, nullptr, q_ws, k_ws, vt_ws, Mm, 3 * Cc, Cc);
  k_attn<<<dim3(64, 16), 256, 0, stream>>>(q_ws, k_ws, vt_ws, y_ws);
  k_gemm<1><<<dim3(Cc / 128, Mm / 128), 256, 0, stream>>>(
      y_ws, wprojT, out, nullptr, nullptr, nullptr, Mm, Cc, Cc);
}

// Round 13
// 283.725 us; speedup vs baseline: 1.8905x; 1.0276x over previous
//
#include <hip/hip_runtime.h>
#include <hip/hip_bf16.h>
#include <stdint.h>

using short8 = __attribute__((ext_vector_type(8))) short;
using s4vec  = __attribute__((ext_vector_type(4))) short;
using f32x4  = __attribute__((ext_vector_type(4))) float;
using u32x2  = __attribute__((ext_vector_type(2))) unsigned int;
using u32x4  = __attribute__((ext_vector_type(4))) unsigned int;

__device__ inline unsigned short f2bf(float f) {
  union { float f; unsigned int u; } v; v.f = f;
  unsigned int r = v.u + 0x7FFFu + ((v.u >> 16) & 1u);
  return (unsigned short)(r >> 16);
}
__device__ inline float bf2f(unsigned short u) {
  union { unsigned int u; float f; } v; v.u = ((unsigned int)u) << 16;
  return v.f;
}
__device__ inline unsigned int pack_bf16(float lo, float hi) {
  union { __hip_bfloat162 b; unsigned int u; } cv;
  cv.b = __float22bfloat162_rn(make_float2(lo, hi));  // .x -> low 16 bits
  return cv.u;
}

#if __has_builtin(__builtin_amdgcn_global_load_lds)
#define HAVE_GLOAD_LDS 1
// CK-style: global (AS1) per-lane src, wave-uniform LDS (AS3) base; HW writes base+lane*16.
__device__ inline void gload_lds16(const unsigned short* g, unsigned short* l) {
  auto gp = (const __attribute__((address_space(1))) unsigned int*)(uintptr_t)g;
  auto lp = (__attribute__((address_space(3))) unsigned int*)(uintptr_t)l;
  __builtin_amdgcn_global_load_lds(gp, lp, 16, 0, 0);
}
#else
#define HAVE_GLOAD_LDS 0
#endif

// ---------------- elementwise f32 -> bf16 ----------------
__global__ __launch_bounds__(256) void k_convert(const float* __restrict__ in,
                                                 unsigned short* __restrict__ out, int n) {
  int i = (blockIdx.x * 256 + threadIdx.x) * 8;
  if (i >= n) return;
  float4 a = *(const float4*)(in + i);
  float4 b = *(const float4*)(in + i + 4);
  short8 o;
  o[0] = (short)f2bf(a.x); o[1] = (short)f2bf(a.y);
  o[2] = (short)f2bf(a.z); o[3] = (short)f2bf(a.w);
  o[4] = (short)f2bf(b.x); o[5] = (short)f2bf(b.y);
  o[6] = (short)f2bf(b.z); o[7] = (short)f2bf(b.w);
  *(short8*)(out + i) = o;
}

// ---------------- transpose-convert: in[R][C] f32 -> out[C][R] bf16 ----------------
__global__ __launch_bounds__(256) void k_transpose(const float* __restrict__ in,
                                                   unsigned short* __restrict__ out,
                                                   int R, int C) {
  __shared__ float t[32][33];
  int c0 = blockIdx.x * 32, r0 = blockIdx.y * 32;
  int cl = threadIdx.x & 31, rl = threadIdx.x >> 5;  // rl 0..7
  for (int p = 0; p < 4; ++p)
    t[rl + p * 8][cl] = in[(size_t)(r0 + rl + p * 8) * C + c0 + cl];
  __syncthreads();
  for (int p = 0; p < 4; ++p)
    out[(size_t)(c0 + rl + p * 8) * R + r0 + cl] = f2bf(t[cl][rl + p * 8]);
}

// ---------------- bf16 GEMM: C[M,N] = A[M,K] * Bt[N,K]^T ----------------
// BK=64: half the K-iterations -> half the vmcnt(0)+barrier drains.
// XOR block swizzle (rule #21): logical (row, cb) stored at physical cb^(row&7) (16B
// units); gload_lds keeps a LINEAR dest, the SOURCE global col is inverse-swizzled,
// fragment reads apply the same XOR. Read bank-group = (h*4+lg)^(lr&7): 8 groups per
// 16-lane quad -> 2-way = free. (Unswizzled [128][64] would be a 16-way conflict.)
// MODE 0: scatter epilogue into q/k ws [B,H,T,D] and v ws [B,H,D,T] (V transposed)
// MODE 1: plain fp32 C write
template <int MODE>
__global__ __launch_bounds__(256) void k_gemm(
    const unsigned short* __restrict__ A, const unsigned short* __restrict__ Bt,
    float* __restrict__ Cf,
    unsigned short* __restrict__ q_ws, unsigned short* __restrict__ k_ws,
    unsigned short* __restrict__ v_ws, int M, int N, int K) {
  __shared__ __align__(16) unsigned short As[128 * 64];
  __shared__ __align__(16) unsigned short Bs[128 * 64];
  const int tid = threadIdx.x;
  const int w = tid >> 6, l = tid & 63;
  const int lr = l & 15, lg = l >> 4;
  const int wr = w >> 1, wc = w & 1;
  const int m0 = blockIdx.y * 128, n0 = blockIdx.x * 128;
  // fragment-read swizzled col offsets (shorts) for h=0,1: ((h*4+lg)^(lr&7))*8
  const int fcg0 = ((0 * 4 + lg) ^ (lr & 7)) * 8;
  const int fcg1 = ((1 * 4 + lg) ^ (lr & 7)) * 8;
  f32x4 acc[4][4] = {};
  for (int k0 = 0; k0 < K; k0 += 64) {
#pragma unroll
    for (int rep = 0; rep < 4; ++rep) {
      int e = rep * 2048 + tid * 8;        // flat physical short index
      int row = e >> 6, cbp = (e >> 3) & 7;
      int kk = ((cbp ^ (row & 7)) * 8);    // logical source col (inverse swizzle)
      const unsigned short* ga = A + (size_t)(m0 + row) * K + k0 + kk;
      const unsigned short* gb = Bt + (size_t)(n0 + row) * K + k0 + kk;
#if HAVE_GLOAD_LDS
      // wave-uniform LDS base (shorts): rep*2048 + w*512; lane writes base + lane*16B
      unsigned short* la = As + rep * 2048 + w * 512;
      unsigned short* lb = Bs + rep * 2048 + w * 512;
      gload_lds16(ga, la);
      gload_lds16(gb, lb);
#else
      *(short8*)&As[e] = *(const short8*)ga;
      *(short8*)&Bs[e] = *(const short8*)gb;
#endif
    }
    __syncthreads();
#pragma unroll
    for (int h = 0; h < 2; ++h) {
      int fcg = h ? fcg1 : fcg0;
      short8 af[4], bf[4];
#pragma unroll
      for (int i = 0; i < 4; ++i)
        af[i] = *(const short8*)&As[(wr * 64 + i * 16 + lr) * 64 + fcg];
#pragma unroll
      for (int j = 0; j < 4; ++j)
        bf[j] = *(const short8*)&Bs[(wc * 64 + j * 16 + lr) * 64 + fcg];
#pragma unroll
      for (int i = 0; i < 4; ++i)
#pragma unroll
        for (int j = 0; j < 4; ++j)
          acc[i][j] = __builtin_amdgcn_mfma_f32_16x16x32_bf16(af[i], bf[j], acc[i][j], 0, 0, 0);
    }
    __syncthreads();
  }
  // C/D layout: col = lane&15, row = (lane>>4)*4 + reg
  if constexpr (MODE == 1) {
#pragma unroll
    for (int i = 0; i < 4; ++i)
#pragma unroll
      for (int j = 0; j < 4; ++j)
#pragma unroll
        for (int r = 0; r < 4; ++r) {
          int row = m0 + wr * 64 + i * 16 + lg * 4 + r;
          int col = n0 + wc * 64 + j * 16 + lr;
          Cf[(size_t)row * N + col] = acc[i][j][r];
        }
  } else {
#pragma unroll
    for (int i = 0; i < 4; ++i)
#pragma unroll
      for (int j = 0; j < 4; ++j) {
        int row0 = m0 + wr * 64 + i * 16 + lg * 4;
        int col = n0 + wc * 64 + j * 16 + lr;
        int b = row0 >> 11, t = row0 & 2047;
        int sect = col >> 10, c = col & 1023;
        int h = c >> 6, d = c & 63;
        if (sect == 2) {
          s4vec pv;
#pragma unroll
          for (int r = 0; r < 4; ++r) pv[r] = (short)f2bf(acc[i][j][r]);
          *(s4vec*)(v_ws + (((size_t)(b * 16 + h)) * 64 + d) * 2048 + t) = pv;
        } else {
          unsigned short* dst = (sect == 0) ? q_ws : k_ws;
#pragma unroll
          for (int r = 0; r < 4; ++r)
            dst[(((size_t)(b * 16 + h)) * 2048 + t + r) * 64 + d] = f2bf(acc[i][j][r]);
        }
      }
  }
}

// ---------------- causal flash attention, swapped-QK^T, in-register softmax ----------------
// grid: (bh=64, qt=16); block 256 = 4 waves, wave owns 32 q-rows. KVBLK=64.
// Swizzled-LDS P round-trip; XOR-swizzled Ks/Vs; T13 defer-max; T14 async-STAGE.
__global__ __launch_bounds__(256) void k_attn(
    const unsigned short* __restrict__ q_ws, const unsigned short* __restrict__ k_ws,
    const unsigned short* __restrict__ vt_ws, unsigned short* __restrict__ y_ws) {
  __shared__ __align__(16) unsigned short Ks[64][64];  // K tile [t][d], XOR-swizzled
  __shared__ __align__(16) unsigned short Vs[64][64];  // V^T tile [d][t], XOR-swizzled
  __shared__ __align__(16) unsigned int   Ps[4][32][32];  // per-wave P [q][k-word], XOR-swz
  const int bh = blockIdx.x;
  const int q0 = blockIdx.y * 128;
  const int tid = threadIdx.x, w = tid >> 6, l = tid & 63;
  const int lr = l & 15, lg = l >> 4;
  const unsigned short* Qp = q_ws + ((size_t)bh * 2048 + q0 + w * 32) * 64;
  const unsigned short* Kp = k_ws + (size_t)bh * 2048 * 64;
  const unsigned short* Vtp = vt_ws + (size_t)bh * 64 * 2048;
  // Q fragments (B-operand), pre-scaled by 1/sqrt(64)=0.125 (exact in bf16)
  short8 qf[2][2];
#pragma unroll
  for (int i = 0; i < 2; ++i)
#pragma unroll
    for (int ks = 0; ks < 2; ++ks) {
      short8 v = *(const short8*)(Qp + (i * 16 + lr) * 64 + ks * 32 + lg * 8);
#pragma unroll
      for (int e = 0; e < 8; ++e)
        v[e] = (short)f2bf(bf2f((unsigned short)v[e]) * 0.125f);
      qf[i][ks] = v;
    }
  float m_st[2] = {-INFINITY, -INFINITY}, l_st[2] = {0.f, 0.f};
  f32x4 o[2][4] = {};  // O^T: rows d = jd*16+lg*4+r, cols q = i*16+lr
  const int nt = (q0 >> 6) + 2;  // tiles 0..2*qt+1
  const int qhi = q0 + w * 32 + 31;
  // staging coords: row = srow + rep*32, 16B col-block cbl, swizzled by row&7 (= srow&7)
  const int srow = tid >> 3, cbl = tid & 7;
  const int scc = cbl * 8;                       // global source col (shorts)
  const int scw = ((cbl ^ (srow & 7)) * 8);      // swizzled LDS col (shorts)
  // fragment-read swizzled cols (16B units): cb' = (ks*4+lg) ^ (lr&7)
  const int fc0 = ((0 * 4 + lg) ^ (lr & 7)) * 8; // ks=0
  const int fc1 = ((1 * 4 + lg) ^ (lr & 7)) * 8; // ks=1
  // prologue: load tile 0 into regs
  short8 kreg[2], vreg[2];
#pragma unroll
  for (int rep = 0; rep < 2; ++rep) {
    int row = srow + rep * 32;
    kreg[rep] = *(const short8*)(Kp + (size_t)row * 64 + scc);
    vreg[rep] = *(const short8*)(Vtp + (size_t)row * 2048 + scc);
  }
  for (int kt = 0; kt < nt; ++kt) {
    __syncthreads();  // prior tile's LDS reads complete (noop at kt=0)
#pragma unroll
    for (int rep = 0; rep < 2; ++rep) {
      int row = srow + rep * 32;
      *(short8*)&Ks[row][scw] = kreg[rep];
      *(short8*)&Vs[row][scw] = vreg[rep];
    }
    __syncthreads();
    // issue next tile's global loads now; latency hides under compute below
    {
      int ktn = (kt + 1 < nt) ? kt + 1 : kt;
#pragma unroll
      for (int rep = 0; rep < 2; ++rep) {
        int row = srow + rep * 32;
        kreg[rep] = *(const short8*)(Kp + (size_t)(ktn * 64 + row) * 64 + scc);
        vreg[rep] = *(const short8*)(Vtp + (size_t)row * 2048 + ktn * 64 + scc);
      }
    }
    if (kt * 64 > qhi) continue;  // wave-level causal skip (barriers already passed)
    // S^T = K * Q^T : s[j][i] holds S[k = kt*64 + j*16 + lg*4 + r][q = q0+w*32 + i*16 + lr]
    f32x4 s[4][2] = {};
#pragma unroll
    for (int ks = 0; ks < 2; ++ks) {
      int fc = ks ? fc1 : fc0;
      short8 kf[4];
#pragma unroll
      for (int j = 0; j < 4; ++j) kf[j] = *(const short8*)&Ks[j * 16 + lr][fc];
#pragma unroll
      for (int j = 0; j < 4; ++j)
#pragma unroll
        for (int i = 0; i < 2; ++i)
          s[j][i] = __builtin_amdgcn_mfma_f32_16x16x32_bf16(kf[j], qf[i][ks], s[j][i], 0, 0, 0);
    }
    if (kt * 64 + 63 > q0 + w * 32) {  // tile touches the diagonal -> mask
#pragma unroll
      for (int j = 0; j < 4; ++j)
#pragma unroll
        for (int i = 0; i < 2; ++i) {
          int gq = q0 + w * 32 + i * 16 + lr;
          int gk0 = kt * 64 + j * 16 + lg * 4;
#pragma unroll
          for (int r = 0; r < 4; ++r)
            if (gk0 + r > gq) s[j][i][r] = -INFINITY;
        }
    }
    union U4S8 { u32x4 u; short8 s; };
    short8 pa[2][2];
#pragma unroll
    for (int i = 0; i < 2; ++i) {
      // row q = i*16+lr max: in-lane fold over 16 + 2 shfl (replicas differ in lg)
      float tm = s[0][i][0];
#pragma unroll
      for (int j = 0; j < 4; ++j)
#pragma unroll
        for (int r = 0; r < 4; ++r) tm = fmaxf(tm, s[j][i][r]);
      tm = fmaxf(tm, __shfl_xor(tm, 16));
      tm = fmaxf(tm, __shfl_xor(tm, 32));
      // T13 defer-max: only rescale when some row grew its max by >8
      if (!__all(tm <= m_st[i] + 8.f)) {
        float nm = fmaxf(m_st[i], tm);
        float corr = __expf(m_st[i] - nm);
        m_st[i] = nm;
        l_st[i] *= corr;
        // O^T cols are q = lr -> corr applies lane-locally, no gather
#pragma unroll
        for (int jd = 0; jd < 4; ++jd)
#pragma unroll
          for (int r = 0; r < 4; ++r) o[i][jd][r] *= corr;
      }
      float ts = 0.f;
#pragma unroll
      for (int j = 0; j < 4; ++j)
#pragma unroll
        for (int r = 0; r < 4; ++r) {
          float p = __expf(s[j][i][r] - m_st[i]);
          s[j][i][r] = p;
          ts += p;
        }
      ts += __shfl_xor(ts, 16);
      ts += __shfl_xor(ts, 32);
      l_st[i] += ts;
      // P -> per-wave LDS (bf16 packed), XOR-swizzled u64 units: u = (j*4+lg) ^ (lr&14)
      unsigned int* prow = &Ps[w][i * 16 + lr][0];
#pragma unroll
      for (int j = 0; j < 4; ++j) {
        u32x2 v2;
        v2[0] = pack_bf16(s[j][i][0], s[j][i][1]);
        v2[1] = pack_bf16(s[j][i][2], s[j][i][3]);
        *(u32x2*)(prow + (((j * 4 + lg) ^ (lr & 14)) * 2)) = v2;
      }
      // read back operand fragments: b128 at u64 pair base (ks*8+lg*2) ^ (lr&14) (even)
#pragma unroll
      for (int ks = 0; ks < 2; ++ks) {
        U4S8 cv;
        cv.u = *(const u32x4*)(prow + (((ks * 8 + lg * 2) ^ (lr & 14)) * 2));
        pa[i][ks] = cv.s;
      }
    }
    // O^T += V^T * P^T  (A = V^T frags from Vs, B = P^T frags = pa)
#pragma unroll
    for (int ks = 0; ks < 2; ++ks) {
      int fc = ks ? fc1 : fc0;
      short8 vf[4];
#pragma unroll
      for (int jd = 0; jd < 4; ++jd) vf[jd] = *(const short8*)&Vs[jd * 16 + lr][fc];
#pragma unroll
      for (int i = 0; i < 2; ++i)
#pragma unroll
        for (int jd = 0; jd < 4; ++jd)
          o[i][jd] = __builtin_amdgcn_mfma_f32_16x16x32_bf16(vf[jd], pa[i][ks], o[i][jd], 0, 0, 0);
    }
  }
  // epilogue: O^T -> y[b, t=q0+w*32+i*16+lr, h*64 + jd*16 + lg*4 + r]; 8B vector stores
  int b = bh >> 4, h = bh & 15;
#pragma unroll
  for (int i = 0; i < 2; ++i) {
    float li = 1.f / l_st[i];
    int t = q0 + w * 32 + i * 16 + lr;
#pragma unroll
    for (int jd = 0; jd < 4; ++jd) {
      s4vec pv;
#pragma unroll
      for (int r = 0; r < 4; ++r) pv[r] = (short)f2bf(o[i][jd][r] * li);
      *(s4vec*)(y_ws + ((size_t)(b * 2048 + t)) * 1024 + h * 64 + jd * 16 + lg * 4) = pv;
    }
  }
}

extern "C" void kernel_launch(void* const* d_in, const int* in_sizes, int n_in,
                              void* d_out, int out_size, void* d_ws, size_t ws_size,
                              hipStream_t stream) {
  const float* x      = (const float*)d_in[0];
  const float* w_qkv  = (const float*)d_in[1];
  const float* w_proj = (const float*)d_in[2];
  float* out = (float*)d_out;
  const int Mm = 8192, Cc = 1024;  // B*T, C
  unsigned short* ws     = (unsigned short*)d_ws;
  unsigned short* xb     = ws;                                  // [8192,1024] bf16
  unsigned short* wqkvT  = xb + (size_t)Mm * Cc;                // [3072,1024] bf16
  unsigned short* wprojT = wqkvT + (size_t)3 * Cc * Cc;         // [1024,1024] bf16
  unsigned short* q_ws   = wprojT + (size_t)Cc * Cc;            // [B,H,T,D] bf16
  unsigned short* k_ws   = q_ws + (size_t)Mm * Cc;              // [B,H,T,D] bf16
  unsigned short* vt_ws  = k_ws + (size_t)Mm * Cc;              // [B,H,D,T] bf16 (transposed)
  unsigned short* y_ws   = xb;  // alias: xb dead after GEMM1

  k_convert<<<dim3(Mm * Cc / 8 / 256), 256, 0, stream>>>(x, xb, Mm * Cc);
  k_transpose<<<dim3(3 * Cc / 32, Cc / 32), 256, 0, stream>>>(w_qkv, wqkvT, Cc, 3 * Cc);
  k_transpose<<<dim3(Cc / 32, Cc / 32), 256, 0, stream>>>(w_proj, wprojT, Cc, Cc);
  k_gemm<0><<<dim3(3 * Cc / 128, Mm / 128), 256, 0, stream>>>(
      xb, wqkvT, nullptr, q_ws, k_ws, vt_ws, Mm, 3 * Cc, Cc);
  k_attn<<<dim3(64, 16), 256, 0, stream>>>(q_ws, k_ws, vt_ws, y_ws);
  k_gemm<1><<<dim3(Cc / 128, Mm / 128), 256, 0, stream>>>(
      y_ws, wprojT, out, nullptr, nullptr, nullptr, Mm, Cc, Cc);
}

// Round 14
// 265.455 us; speedup vs baseline: 2.0206x; 1.0688x over previous
//
#include <hip/hip_runtime.h>
#include <hip/hip_bf16.h>
#include <stdint.h>

using short8 = __attribute__((ext_vector_type(8))) short;
using s4vec  = __attribute__((ext_vector_type(4))) short;
using f32x4  = __attribute__((ext_vector_type(4))) float;
using u32x2  = __attribute__((ext_vector_type(2))) unsigned int;
using u32x4  = __attribute__((ext_vector_type(4))) unsigned int;

__device__ inline unsigned short f2bf(float f) {
  union { float f; unsigned int u; } v; v.f = f;
  unsigned int r = v.u + 0x7FFFu + ((v.u >> 16) & 1u);
  return (unsigned short)(r >> 16);
}
__device__ inline float bf2f(unsigned short u) {
  union { unsigned int u; float f; } v; v.u = ((unsigned int)u) << 16;
  return v.f;
}
__device__ inline unsigned int pack_bf16(float lo, float hi) {
  union { __hip_bfloat162 b; unsigned int u; } cv;
  cv.b = __float22bfloat162_rn(make_float2(lo, hi));  // .x -> low 16 bits
  return cv.u;
}

#if __has_builtin(__builtin_amdgcn_global_load_lds)
#define HAVE_GLOAD_LDS 1
// CK-style: global (AS1) per-lane src, wave-uniform LDS (AS3) base; HW writes base+lane*16.
__device__ inline void gload_lds16(const unsigned short* g, unsigned short* l) {
  auto gp = (const __attribute__((address_space(1))) unsigned int*)(uintptr_t)g;
  auto lp = (__attribute__((address_space(3))) unsigned int*)(uintptr_t)l;
  __builtin_amdgcn_global_load_lds(gp, lp, 16, 0, 0);
}
#else
#define HAVE_GLOAD_LDS 0
#endif

// ---------------- elementwise f32 -> bf16 ----------------
__global__ __launch_bounds__(256) void k_convert(const float* __restrict__ in,
                                                 unsigned short* __restrict__ out, int n) {
  int i = (blockIdx.x * 256 + threadIdx.x) * 8;
  if (i >= n) return;
  float4 a = *(const float4*)(in + i);
  float4 b = *(const float4*)(in + i + 4);
  short8 o;
  o[0] = (short)f2bf(a.x); o[1] = (short)f2bf(a.y);
  o[2] = (short)f2bf(a.z); o[3] = (short)f2bf(a.w);
  o[4] = (short)f2bf(b.x); o[5] = (short)f2bf(b.y);
  o[6] = (short)f2bf(b.z); o[7] = (short)f2bf(b.w);
  *(short8*)(out + i) = o;
}

// ---------------- transpose-convert: in[R][C] f32 -> out[C][R] bf16 ----------------
__global__ __launch_bounds__(256) void k_transpose(const float* __restrict__ in,
                                                   unsigned short* __restrict__ out,
                                                   int R, int C) {
  __shared__ float t[32][33];
  int c0 = blockIdx.x * 32, r0 = blockIdx.y * 32;
  int cl = threadIdx.x & 31, rl = threadIdx.x >> 5;  // rl 0..7
  for (int p = 0; p < 4; ++p)
    t[rl + p * 8][cl] = in[(size_t)(r0 + rl + p * 8) * C + c0 + cl];
  __syncthreads();
  for (int p = 0; p < 4; ++p)
    out[(size_t)(c0 + rl + p * 8) * R + r0 + cl] = f2bf(t[cl][rl + p * 8]);
}

// ---------------- bf16 GEMM: C[M,N] = A[M,K] * Bt[N,K]^T ----------------
// 2-phase double-buffered pipeline (T3-minimum): issue tile t+1's global_load_lds
// BEFORE computing tile t, so load flight hides under the 32-MFMA compute; ONE
// barrier per K-step (its vmcnt(0) drain lands after compute, not before).
// BK=64; XOR block swizzle (16B unit cb ^= row&7): linear gload_lds dest +
// inverse-swizzled global source + swizzled fragment reads (2-way banks = free).
// LDS = 2 x (16+16) KB = 64 KB.
// MODE 0: scatter epilogue into q/k ws [B,H,T,D] and v ws [B,H,D,T] (V transposed)
// MODE 1: plain fp32 C write
template <int MODE>
__global__ __launch_bounds__(256) void k_gemm(
    const unsigned short* __restrict__ A, const unsigned short* __restrict__ Bt,
    float* __restrict__ Cf,
    unsigned short* __restrict__ q_ws, unsigned short* __restrict__ k_ws,
    unsigned short* __restrict__ v_ws, int M, int N, int K) {
  __shared__ __align__(16) unsigned short As[2][128 * 64];
  __shared__ __align__(16) unsigned short Bs[2][128 * 64];
  const int tid = threadIdx.x;
  const int w = tid >> 6, l = tid & 63;
  const int lr = l & 15, lg = l >> 4;
  const int wr = w >> 1, wc = w & 1;
  const int m0 = blockIdx.y * 128, n0 = blockIdx.x * 128;
  // fragment-read swizzled col offsets (shorts) for h=0,1: ((h*4+lg)^(lr&7))*8
  const int fcg0 = ((0 * 4 + lg) ^ (lr & 7)) * 8;
  const int fcg1 = ((1 * 4 + lg) ^ (lr & 7)) * 8;
  f32x4 acc[4][4] = {};

  auto stage = [&](int buf, int k0) {
#pragma unroll
    for (int rep = 0; rep < 4; ++rep) {
      int e = rep * 2048 + tid * 8;        // flat physical short index
      int row = e >> 6, cbp = (e >> 3) & 7;
      int kk = ((cbp ^ (row & 7)) * 8);    // logical source col (inverse swizzle)
      const unsigned short* ga = A + (size_t)(m0 + row) * K + k0 + kk;
      const unsigned short* gb = Bt + (size_t)(n0 + row) * K + k0 + kk;
#if HAVE_GLOAD_LDS
      // wave-uniform LDS base (shorts): rep*2048 + w*512; lane writes base + lane*16B
      unsigned short* la = &As[buf][0] + rep * 2048 + w * 512;
      unsigned short* lb = &Bs[buf][0] + rep * 2048 + w * 512;
      gload_lds16(ga, la);
      gload_lds16(gb, lb);
#else
      *(short8*)&As[buf][e] = *(const short8*)ga;
      *(short8*)&Bs[buf][e] = *(const short8*)gb;
#endif
    }
  };

  const int NT = K >> 6;
  stage(0, 0);
  __syncthreads();  // tile 0 resident
  int cur = 0;
  for (int t = 0; t < NT; ++t) {
    if (t + 1 < NT) stage(cur ^ 1, (t + 1) << 6);  // async: flies during compute below
    const unsigned short* Ac = &As[cur][0];
    const unsigned short* Bc = &Bs[cur][0];
#pragma unroll
    for (int h = 0; h < 2; ++h) {
      int fcg = h ? fcg1 : fcg0;
      short8 af[4], bf[4];
#pragma unroll
      for (int i = 0; i < 4; ++i)
        af[i] = *(const short8*)&Ac[(wr * 64 + i * 16 + lr) * 64 + fcg];
#pragma unroll
      for (int j = 0; j < 4; ++j)
        bf[j] = *(const short8*)&Bc[(wc * 64 + j * 16 + lr) * 64 + fcg];
#pragma unroll
      for (int i = 0; i < 4; ++i)
#pragma unroll
        for (int j = 0; j < 4; ++j)
          acc[i][j] = __builtin_amdgcn_mfma_f32_16x16x32_bf16(af[i], bf[j], acc[i][j], 0, 0, 0);
    }
    __syncthreads();  // drains next-tile loads; all reads of cur done before overwrite
    cur ^= 1;
  }
  // C/D layout: col = lane&15, row = (lane>>4)*4 + reg
  if constexpr (MODE == 1) {
#pragma unroll
    for (int i = 0; i < 4; ++i)
#pragma unroll
      for (int j = 0; j < 4; ++j)
#pragma unroll
        for (int r = 0; r < 4; ++r) {
          int row = m0 + wr * 64 + i * 16 + lg * 4 + r;
          int col = n0 + wc * 64 + j * 16 + lr;
          Cf[(size_t)row * N + col] = acc[i][j][r];
        }
  } else {
#pragma unroll
    for (int i = 0; i < 4; ++i)
#pragma unroll
      for (int j = 0; j < 4; ++j) {
        int row0 = m0 + wr * 64 + i * 16 + lg * 4;
        int col = n0 + wc * 64 + j * 16 + lr;
        int b = row0 >> 11, t = row0 & 2047;
        int sect = col >> 10, c = col & 1023;
        int h = c >> 6, d = c & 63;
        if (sect == 2) {
          s4vec pv;
#pragma unroll
          for (int r = 0; r < 4; ++r) pv[r] = (short)f2bf(acc[i][j][r]);
          *(s4vec*)(v_ws + (((size_t)(b * 16 + h)) * 64 + d) * 2048 + t) = pv;
        } else {
          unsigned short* dst = (sect == 0) ? q_ws : k_ws;
#pragma unroll
          for (int r = 0; r < 4; ++r)
            dst[(((size_t)(b * 16 + h)) * 2048 + t + r) * 64 + d] = f2bf(acc[i][j][r]);
        }
      }
  }
}

// ---------------- causal flash attention, swapped-QK^T, in-register softmax ----------------
// grid: (bh=64, qt=16); block 256 = 4 waves, wave owns 32 q-rows. KVBLK=64.
// Swizzled-LDS P round-trip; XOR-swizzled Ks/Vs; T13 defer-max; T14 async-STAGE.
__global__ __launch_bounds__(256) void k_attn(
    const unsigned short* __restrict__ q_ws, const unsigned short* __restrict__ k_ws,
    const unsigned short* __restrict__ vt_ws, unsigned short* __restrict__ y_ws) {
  __shared__ __align__(16) unsigned short Ks[64][64];  // K tile [t][d], XOR-swizzled
  __shared__ __align__(16) unsigned short Vs[64][64];  // V^T tile [d][t], XOR-swizzled
  __shared__ __align__(16) unsigned int   Ps[4][32][32];  // per-wave P [q][k-word], XOR-swz
  const int bh = blockIdx.x;
  const int q0 = blockIdx.y * 128;
  const int tid = threadIdx.x, w = tid >> 6, l = tid & 63;
  const int lr = l & 15, lg = l >> 4;
  const unsigned short* Qp = q_ws + ((size_t)bh * 2048 + q0 + w * 32) * 64;
  const unsigned short* Kp = k_ws + (size_t)bh * 2048 * 64;
  const unsigned short* Vtp = vt_ws + (size_t)bh * 64 * 2048;
  // Q fragments (B-operand), pre-scaled by 1/sqrt(64)=0.125 (exact in bf16)
  short8 qf[2][2];
#pragma unroll
  for (int i = 0; i < 2; ++i)
#pragma unroll
    for (int ks = 0; ks < 2; ++ks) {
      short8 v = *(const short8*)(Qp + (i * 16 + lr) * 64 + ks * 32 + lg * 8);
#pragma unroll
      for (int e = 0; e < 8; ++e)
        v[e] = (short)f2bf(bf2f((unsigned short)v[e]) * 0.125f);
      qf[i][ks] = v;
    }
  float m_st[2] = {-INFINITY, -INFINITY}, l_st[2] = {0.f, 0.f};
  f32x4 o[2][4] = {};  // O^T: rows d = jd*16+lg*4+r, cols q = i*16+lr
  const int nt = (q0 >> 6) + 2;  // tiles 0..2*qt+1
  const int qhi = q0 + w * 32 + 31;
  // staging coords: row = srow + rep*32, 16B col-block cbl, swizzled by row&7 (= srow&7)
  const int srow = tid >> 3, cbl = tid & 7;
  const int scc = cbl * 8;                       // global source col (shorts)
  const int scw = ((cbl ^ (srow & 7)) * 8);      // swizzled LDS col (shorts)
  // fragment-read swizzled cols (16B units): cb' = (ks*4+lg) ^ (lr&7)
  const int fc0 = ((0 * 4 + lg) ^ (lr & 7)) * 8; // ks=0
  const int fc1 = ((1 * 4 + lg) ^ (lr & 7)) * 8; // ks=1
  // prologue: load tile 0 into regs
  short8 kreg[2], vreg[2];
#pragma unroll
  for (int rep = 0; rep < 2; ++rep) {
    int row = srow + rep * 32;
    kreg[rep] = *(const short8*)(Kp + (size_t)row * 64 + scc);
    vreg[rep] = *(const short8*)(Vtp + (size_t)row * 2048 + scc);
  }
  for (int kt = 0; kt < nt; ++kt) {
    __syncthreads();  // prior tile's LDS reads complete (noop at kt=0)
#pragma unroll
    for (int rep = 0; rep < 2; ++rep) {
      int row = srow + rep * 32;
      *(short8*)&Ks[row][scw] = kreg[rep];
      *(short8*)&Vs[row][scw] = vreg[rep];
    }
    __syncthreads();
    // issue next tile's global loads now; latency hides under compute below
    {
      int ktn = (kt + 1 < nt) ? kt + 1 : kt;
#pragma unroll
      for (int rep = 0; rep < 2; ++rep) {
        int row = srow + rep * 32;
        kreg[rep] = *(const short8*)(Kp + (size_t)(ktn * 64 + row) * 64 + scc);
        vreg[rep] = *(const short8*)(Vtp + (size_t)row * 2048 + ktn * 64 + scc);
      }
    }
    if (kt * 64 > qhi) continue;  // wave-level causal skip (barriers already passed)
    // S^T = K * Q^T : s[j][i] holds S[k = kt*64 + j*16 + lg*4 + r][q = q0+w*32 + i*16 + lr]
    f32x4 s[4][2] = {};
#pragma unroll
    for (int ks = 0; ks < 2; ++ks) {
      int fc = ks ? fc1 : fc0;
      short8 kf[4];
#pragma unroll
      for (int j = 0; j < 4; ++j) kf[j] = *(const short8*)&Ks[j * 16 + lr][fc];
#pragma unroll
      for (int j = 0; j < 4; ++j)
#pragma unroll
        for (int i = 0; i < 2; ++i)
          s[j][i] = __builtin_amdgcn_mfma_f32_16x16x32_bf16(kf[j], qf[i][ks], s[j][i], 0, 0, 0);
    }
    if (kt * 64 + 63 > q0 + w * 32) {  // tile touches the diagonal -> mask
#pragma unroll
      for (int j = 0; j < 4; ++j)
#pragma unroll
        for (int i = 0; i < 2; ++i) {
          int gq = q0 + w * 32 + i * 16 + lr;
          int gk0 = kt * 64 + j * 16 + lg * 4;
#pragma unroll
          for (int r = 0; r < 4; ++r)
            if (gk0 + r > gq) s[j][i][r] = -INFINITY;
        }
    }
    union U4S8 { u32x4 u; short8 s; };
    short8 pa[2][2];
#pragma unroll
    for (int i = 0; i < 2; ++i) {
      // row q = i*16+lr max: in-lane fold over 16 + 2 shfl (replicas differ in lg)
      float tm = s[0][i][0];
#pragma unroll
      for (int j = 0; j < 4; ++j)
#pragma unroll
        for (int r = 0; r < 4; ++r) tm = fmaxf(tm, s[j][i][r]);
      tm = fmaxf(tm, __shfl_xor(tm, 16));
      tm = fmaxf(tm, __shfl_xor(tm, 32));
      // T13 defer-max: only rescale when some row grew its max by >8
      if (!__all(tm <= m_st[i] + 8.f)) {
        float nm = fmaxf(m_st[i], tm);
        float corr = __expf(m_st[i] - nm);
        m_st[i] = nm;
        l_st[i] *= corr;
        // O^T cols are q = lr -> corr applies lane-locally, no gather
#pragma unroll
        for (int jd = 0; jd < 4; ++jd)
#pragma unroll
          for (int r = 0; r < 4; ++r) o[i][jd][r] *= corr;
      }
      float ts = 0.f;
#pragma unroll
      for (int j = 0; j < 4; ++j)
#pragma unroll
        for (int r = 0; r < 4; ++r) {
          float p = __expf(s[j][i][r] - m_st[i]);
          s[j][i][r] = p;
          ts += p;
        }
      ts += __shfl_xor(ts, 16);
      ts += __shfl_xor(ts, 32);
      l_st[i] += ts;
      // P -> per-wave LDS (bf16 packed), XOR-swizzled u64 units: u = (j*4+lg) ^ (lr&14)
      unsigned int* prow = &Ps[w][i * 16 + lr][0];
#pragma unroll
      for (int j = 0; j < 4; ++j) {
        u32x2 v2;
        v2[0] = pack_bf16(s[j][i][0], s[j][i][1]);
        v2[1] = pack_bf16(s[j][i][2], s[j][i][3]);
        *(u32x2*)(prow + (((j * 4 + lg) ^ (lr & 14)) * 2)) = v2;
      }
      // read back operand fragments: b128 at u64 pair base (ks*8+lg*2) ^ (lr&14) (even)
#pragma unroll
      for (int ks = 0; ks < 2; ++ks) {
        U4S8 cv;
        cv.u = *(const u32x4*)(prow + (((ks * 8 + lg * 2) ^ (lr & 14)) * 2));
        pa[i][ks] = cv.s;
      }
    }
    // O^T += V^T * P^T  (A = V^T frags from Vs, B = P^T frags = pa)
#pragma unroll
    for (int ks = 0; ks < 2; ++ks) {
      int fc = ks ? fc1 : fc0;
      short8 vf[4];
#pragma unroll
      for (int jd = 0; jd < 4; ++jd) vf[jd] = *(const short8*)&Vs[jd * 16 + lr][fc];
#pragma unroll
      for (int i = 0; i < 2; ++i)
#pragma unroll
        for (int jd = 0; jd < 4; ++jd)
          o[i][jd] = __builtin_amdgcn_mfma_f32_16x16x32_bf16(vf[jd], pa[i][ks], o[i][jd], 0, 0, 0);
    }
  }
  // epilogue: O^T -> y[b, t=q0+w*32+i*16+lr, h*64 + jd*16 + lg*4 + r]; 8B vector stores
  int b = bh >> 4, h = bh & 15;
#pragma unroll
  for (int i = 0; i < 2; ++i) {
    float li = 1.f / l_st[i];
    int t = q0 + w * 32 + i * 16 + lr;
#pragma unroll
    for (int jd = 0; jd < 4; ++jd) {
      s4vec pv;
#pragma unroll
      for (int r = 0; r < 4; ++r) pv[r] = (short)f2bf(o[i][jd][r] * li);
      *(s4vec*)(y_ws + ((size_t)(b * 2048 + t)) * 1024 + h * 64 + jd * 16 + lg * 4) = pv;
    }
  }
}

extern "C" void kernel_launch(void* const* d_in, const int* in_sizes, int n_in,
                              void* d_out, int out_size, void* d_ws, size_t ws_size,
                              hipStream_t stream) {
  const float* x      = (const float*)d_in[0];
  const float* w_qkv  = (const float*)d_in[1];
  const float* w_proj = (const float*)d_in[2];
  float* out = (float*)d_out;
  const int Mm = 8192, Cc = 1024;  // B*T, C
  unsigned short* ws     = (unsigned short*)d_ws;
  unsigned short* xb     = ws;                                  // [8192,1024] bf16
  unsigned short* wqkvT  = xb + (size_t)Mm * Cc;                // [3072,1024] bf16
  unsigned short* wprojT = wqkvT + (size_t)3 * Cc * Cc;         // [1024,1024] bf16
  unsigned short* q_ws   = wprojT + (size_t)Cc * Cc;            // [B,H,T,D] bf16
  unsigned short* k_ws   = q_ws + (size_t)Mm * Cc;              // [B,H,T,D] bf16
  unsigned short* vt_ws  = k_ws + (size_t)Mm * Cc;              // [B,H,D,T] bf16 (transposed)
  unsigned short* y_ws   = xb;  // alias: xb dead after GEMM1

  k_convert<<<dim3(Mm * Cc / 8 / 256), 256, 0, stream>>>(x, xb, Mm * Cc);
  k_transpose<<<dim3(3 * Cc / 32, Cc / 32), 256, 0, stream>>>(w_qkv, wqkvT, Cc, 3 * Cc);
  k_transpose<<<dim3(Cc / 32, Cc / 32), 256, 0, stream>>>(w_proj, wprojT, Cc, Cc);
  k_gemm<0><<<dim3(3 * Cc / 128, Mm / 128), 256, 0, stream>>>(
      xb, wqkvT, nullptr, q_ws, k_ws, vt_ws, Mm, 3 * Cc, Cc);
  k_attn<<<dim3(64, 16), 256, 0, stream>>>(q_ws, k_ws, vt_ws, y_ws);
  k_gemm<1><<<dim3(Cc / 128, Mm / 128), 256, 0, stream>>>(
      y_ws, wprojT, out, nullptr, nullptr, nullptr, Mm, Cc, Cc);
}